// Round 6
// baseline (33273.837 us; speedup 1.0000x reference)
//
#include <hip/hip_runtime.h>
#include <math.h>
#include <limits.h>

#define RPB 8      // x-rows per block
#define CCH 64     // train rows per LDS chunk
#define PAD 257    // LDS row stride in floats (256+1 -> bank = (row+f)%32, conflict-free)

// lexicographic (distance, index) compare == jax.lax.top_k stable tie-break
__device__ __forceinline__ bool plt(float da, int ia, float db, int ib) {
    return (da < db) || ((da == db) && (ia < ib));
}

// branchless insert of candidate (d,n) into sorted ascending top-3
__device__ __forceinline__ void insert3(float d, int n, float td[3], int ti[3]) {
    bool b = plt(d, n, td[2], ti[2]);
    float d2 = b ? d : td[2];  int i2 = b ? n : ti[2];
    bool c = plt(d2, i2, td[1], ti[1]);
    float nd1 = c ? d2 : td[1];    int ni1 = c ? i2 : ti[1];
    float nd2 = c ? td[1] : d2;    int ni2 = c ? ti[1] : i2;
    bool e = plt(nd1, ni1, td[0], ti[0]);
    float od0 = td[0]; int oi0 = ti[0];
    td[0] = e ? nd1 : od0;  ti[0] = e ? ni1 : oi0;
    td[1] = e ? od0 : nd1;  ti[1] = e ? oi0 : ni1;
    td[2] = nd2;            ti[2] = ni2;
}

// merge two sorted top-3 lists (b into a), branchless
__device__ __forceinline__ void merge3(float ad[3], int ai[3],
                                       const float bd[3], const int bi[3]) {
    bool b0 = plt(ad[0], ai[0], bd[0], bi[0]);
    float c0d = b0 ? ad[0] : bd[0];  int c0i = b0 ? ai[0] : bi[0];
    float w0d = b0 ? bd[0] : ad[0];  int w0i = b0 ? bi[0] : ai[0];
    bool b1 = plt(ad[1], ai[1], bd[1], bi[1]);
    float m1d = b1 ? ad[1] : bd[1];  int m1i = b1 ? ai[1] : bi[1];
    float M1d = b1 ? bd[1] : ad[1];  int M1i = b1 ? bi[1] : ai[1];
    bool br1 = plt(w0d, w0i, m1d, m1i);
    float r1d = br1 ? w0d : m1d;     int r1i = br1 ? w0i : m1i;
    float t1d = br1 ? m1d : w0d;     int t1i = br1 ? m1i : w0i; // max(w0,m1)
    bool b2 = plt(ad[2], ai[2], bd[2], bi[2]);
    float t2d = b2 ? ad[2] : bd[2];  int t2i = b2 ? ai[2] : bi[2]; // min(a2,b2)
    bool c1 = plt(M1d, M1i, t1d, t1i);
    float ud = c1 ? M1d : t1d;       int ui = c1 ? M1i : t1i;
    bool c2 = plt(ud, ui, t2d, t2i);
    float r2d = c2 ? ud : t2d;       int r2i = c2 ? ui : t2i;
    ad[0] = c0d; ai[0] = c0i;
    ad[1] = r1d; ai[1] = r1i;
    ad[2] = r2d; ai[2] = r2i;
}

// One block = 8 x-rows, scans all N train rows in 64-row LDS chunks.
// Computes left/right norms in-block (no scratch), keeps per-thread top-3,
// merges across the 32 threads sharing a row, writes the 3 gathered LABELS
// per row (as floats) into the stash at the tail of d_out.
// No d_ws usage anywhere. All loop bounds static, all barriers uniform.
__global__ __launch_bounds__(256)
void knn_all(const float* __restrict__ x, const float* __restrict__ t,
             const float* __restrict__ feat, const int* __restrict__ labels,
             float* __restrict__ out, int F, int N, int B, int stashBase) {
    __shared__ float xs[RPB * PAD];    // 8.2 KB
    __shared__ float ts_[CCH * PAD];   // 65.8 KB
    __shared__ float fs[256];
    __shared__ float rw[CCH][4];       // per-wave right-norm partials
    __shared__ float rsum[CCH];
    __shared__ float ls[RPB];

    const int tid  = threadIdx.x;
    const int i    = tid >> 5;         // row 0..7 within block
    const int c0   = tid & 31;         // base column within chunk
    const int wave = tid >> 6;         // 0..3
    const int lane = tid & 63;
    const int row0 = blockIdx.x * RPB;

    // stage 8 x-rows + features (coalesced: consecutive tid -> consecutive f)
    #pragma unroll
    for (int p = 0; p < RPB; ++p)
        xs[p * PAD + tid] = x[(size_t)(row0 + p) * F + tid];
    fs[tid] = feat[tid];
    __syncthreads();

    // left norms, reference summation order (ascending f)
    if (tid < RPB) {
        float s = 0.f;
        for (int f = 0; f < F; ++f) { float v = xs[tid * PAD + f]; s = fmaf(v, v, s); }
        ls[tid] = s;
    }
    __syncthreads();
    const float lv = ls[i];

    float t3d[3]; int t3i[3];
    t3d[0] = t3d[1] = t3d[2] = INFINITY;
    t3i[0] = t3i[1] = t3i[2] = INT_MAX;

    for (int nb = 0; nb < N; nb += CCH) {
        // stage 64 t-rows; accumulate weighted-square partials on the fly
        for (int p = 0; p < CCH; ++p) {
            float v = t[(size_t)(nb + p) * F + tid];
            ts_[p * PAD + tid] = v;
            float e = v * fs[tid];
            e = e * e;
            e += __shfl_xor(e, 1);
            e += __shfl_xor(e, 2);
            e += __shfl_xor(e, 4);
            e += __shfl_xor(e, 8);
            e += __shfl_xor(e, 16);
            e += __shfl_xor(e, 32);
            if (lane == 0) rw[p][wave] = e;
        }
        __syncthreads();
        if (tid < CCH) rsum[tid] = rw[tid][0] + rw[tid][1] + rw[tid][2] + rw[tid][3];
        __syncthreads();

        // dot products: thread (i, c0) handles columns c0 and c0+32.
        // ts_ read: lanes 0..31 -> banks (c0+f)%32 all distinct; lanes 32..63
        // read the same addresses (broadcast). xs read: uniform per half-wave.
        float acc0 = 0.f, acc1 = 0.f;
        #pragma unroll 8
        for (int f = 0; f < F; ++f) {
            float a = xs[i * PAD + f];
            acc0 = fmaf(a, ts_[c0 * PAD + f], acc0);
            acc1 = fmaf(a, ts_[(c0 + 32) * PAD + f], acc1);
        }
        float d0 = sqrtf(lv + rsum[c0])      - 2.0f * acc0;
        float d1 = sqrtf(lv + rsum[c0 + 32]) - 2.0f * acc1;
        insert3(d0, nb + c0,      t3d, t3i);
        insert3(d1, nb + c0 + 32, t3d, t3i);
        __syncthreads();   // before next chunk overwrites ts_
    }

    // merge top-3 across the 32 contiguous lanes sharing row i
    #pragma unroll
    for (int m = 1; m < 32; m <<= 1) {
        float od[3]; int oi[3];
        #pragma unroll
        for (int s = 0; s < 3; ++s) {
            od[s] = __shfl_xor(t3d[s], m);
            oi[s] = __shfl_xor(t3i[s], m);
        }
        merge3(t3d, t3i, od, oi);
    }
    if (c0 == 0) {
        #pragma unroll
        for (int s = 0; s < 3; ++s) {
            int idx = t3i[s];
            idx = idx < 0 ? 0 : (idx >= N ? N - 1 : idx);   // never fault
            out[stashBase + (row0 + i) * 3 + s] = (float)labels[idx];
        }
    }
}

// one-hot rows [0, rowsMain): reads stash, never writes it.
// flat-reshape semantics: out[i] needs stash[i], stash[B+i], stash[2B+i].
__global__ void out_main(float* __restrict__ out, int B, int L,
                         int stashBase, int rowsMain) {
    int tid = blockIdx.x * blockDim.x + threadIdx.x;
    if (tid >= rowsMain * L) return;
    int i = tid / L, c = tid - i * L;
    int s = (int)out[stashBase + i] + (int)out[stashBase + B + i]
          + (int)out[stashBase + 2 * B + i];
    out[tid] = (c == s / 3) ? 1.0f : 0.0f;
}

// single block: buffers the stash slice it needs in LDS, barriers, then
// overwrites the tail cells [rowsMain*L, B*L) (which contain the stash).
__global__ __launch_bounds__(256)
void out_tail(float* __restrict__ out, int B, int L,
              int stashBase, int rowsMain) {
    __shared__ int l0[128], l1[128], l2[128];
    int nt = B - rowsMain;                       // tail rows (62 for B=2048)
    for (int q = threadIdx.x; q < nt * 3; q += 256) {
        int j = q / nt, i = q - j * nt;          // j = which of the 3 slices
        int v = (int)out[stashBase + j * B + rowsMain + i];
        if (j == 0) l0[i] = v; else if (j == 1) l1[i] = v; else l2[i] = v;
    }
    __syncthreads();
    int base = rowsMain * L;
    for (int e = threadIdx.x; e < B * L - base; e += 256) {
        int rr = (base + e) / L - rowsMain, c = (base + e) % L;
        int s = l0[rr] + l1[rr] + l2[rr];
        out[base + e] = (c == s / 3) ? 1.0f : 0.0f;
    }
}

extern "C" void kernel_launch(void* const* d_in, const int* in_sizes, int n_in,
                              void* d_out, int out_size, void* d_ws, size_t ws_size,
                              hipStream_t stream) {
    const float* x      = (const float*)d_in[0];
    const float* t      = (const float*)d_in[1];
    const float* feat   = (const float*)d_in[2];
    const int*   labels = (const int*)d_in[3];
    float*       out    = (float*)d_out;
    const int F = in_sizes[2];           // 256
    const int B = in_sizes[0] / F;       // 2048
    const int N = in_sizes[3];           // 65536
    const int L = out_size / B;          // 100

    const int stashBase = out_size - 3 * B;   // 3B labels stashed in d_out tail
    const int rowsMain  = stashBase / L;      // one-hot rows untouched by stash

    knn_all<<<B / RPB, 256, 0, stream>>>(x, t, feat, labels, out,
                                         F, N, B, stashBase);
    out_main<<<(rowsMain * L + 255) / 256, 256, 0, stream>>>(
        out, B, L, stashBase, rowsMain);
    out_tail<<<1, 256, 0, stream>>>(out, B, L, stashBase, rowsMain);
}

// Round 11
// 33263.721 us; speedup vs baseline: 1.0003x; 1.0003x over previous
//
#include <hip/hip_runtime.h>
#include <math.h>
#include <limits.h>

#define RPB 8      // x-rows per block
#define CCH 64     // train rows per LDS chunk
#define PAD 257    // LDS row stride in floats (256+1 -> bank = (row+f)%32, conflict-free)

// lexicographic (distance, index) compare == jax.lax.top_k stable tie-break
__device__ __forceinline__ bool plt(float da, int ia, float db, int ib) {
    return (da < db) || ((da == db) && (ia < ib));
}

// branchless insert of candidate (d,n) into sorted ascending top-3
__device__ __forceinline__ void insert3(float d, int n, float td[3], int ti[3]) {
    bool b = plt(d, n, td[2], ti[2]);
    float d2 = b ? d : td[2];  int i2 = b ? n : ti[2];
    bool c = plt(d2, i2, td[1], ti[1]);
    float nd1 = c ? d2 : td[1];    int ni1 = c ? i2 : ti[1];
    float nd2 = c ? td[1] : d2;    int ni2 = c ? ti[1] : i2;
    bool e = plt(nd1, ni1, td[0], ti[0]);
    float od0 = td[0]; int oi0 = ti[0];
    td[0] = e ? nd1 : od0;  ti[0] = e ? ni1 : oi0;
    td[1] = e ? od0 : nd1;  ti[1] = e ? oi0 : ni1;
    td[2] = nd2;            ti[2] = ni2;
}

// merge two sorted top-3 lists (b into a), branchless
__device__ __forceinline__ void merge3(float ad[3], int ai[3],
                                       const float bd[3], const int bi[3]) {
    bool b0 = plt(ad[0], ai[0], bd[0], bi[0]);
    float c0d = b0 ? ad[0] : bd[0];  int c0i = b0 ? ai[0] : bi[0];
    float w0d = b0 ? bd[0] : ad[0];  int w0i = b0 ? bi[0] : ai[0];
    bool b1 = plt(ad[1], ai[1], bd[1], bi[1]);
    float m1d = b1 ? ad[1] : bd[1];  int m1i = b1 ? ai[1] : bi[1];
    float M1d = b1 ? bd[1] : ad[1];  int M1i = b1 ? bi[1] : ai[1];
    bool br1 = plt(w0d, w0i, m1d, m1i);
    float r1d = br1 ? w0d : m1d;     int r1i = br1 ? w0i : m1i;
    float t1d = br1 ? m1d : w0d;     int t1i = br1 ? m1i : w0i; // max(w0,m1)
    bool b2 = plt(ad[2], ai[2], bd[2], bi[2]);
    float t2d = b2 ? ad[2] : bd[2];  int t2i = b2 ? ai[2] : bi[2]; // min(a2,b2)
    bool c1 = plt(M1d, M1i, t1d, t1i);
    float ud = c1 ? M1d : t1d;       int ui = c1 ? M1i : t1i;
    bool c2 = plt(ud, ui, t2d, t2i);
    float r2d = c2 ? ud : t2d;       int r2i = c2 ? ui : t2i;
    ad[0] = c0d; ai[0] = c0i;
    ad[1] = r1d; ai[1] = r1i;
    ad[2] = r2d; ai[2] = r2i;
}

// One block = 8 x-rows, scans all N train rows in 64-row LDS chunks.
// Computes left/right norms in-block (no scratch), keeps per-thread top-3,
// merges across the 32 threads sharing a row, writes the 3 gathered LABELS
// per row (as floats) into the stash at the tail of d_out.
// No d_ws usage anywhere. All loop bounds static, all barriers uniform.
__global__ __launch_bounds__(256)
void knn_all(const float* __restrict__ x, const float* __restrict__ t,
             const float* __restrict__ feat, const int* __restrict__ labels,
             float* __restrict__ out, int F, int N, int B, int stashBase) {
    __shared__ float xs[RPB * PAD];    // 8.2 KB
    __shared__ float ts_[CCH * PAD];   // 65.8 KB
    __shared__ float fs[256];
    __shared__ float rw[CCH][4];       // per-wave right-norm partials
    __shared__ float rsum[CCH];
    __shared__ float ls[RPB];

    const int tid  = threadIdx.x;
    const int i    = tid >> 5;         // row 0..7 within block
    const int c0   = tid & 31;         // base column within chunk
    const int wave = tid >> 6;         // 0..3
    const int lane = tid & 63;
    const int row0 = blockIdx.x * RPB;

    // stage 8 x-rows + features (coalesced: consecutive tid -> consecutive f)
    #pragma unroll
    for (int p = 0; p < RPB; ++p)
        xs[p * PAD + tid] = x[(size_t)(row0 + p) * F + tid];
    fs[tid] = feat[tid];
    __syncthreads();

    // left norms, reference summation order (ascending f)
    if (tid < RPB) {
        float s = 0.f;
        for (int f = 0; f < F; ++f) { float v = xs[tid * PAD + f]; s = fmaf(v, v, s); }
        ls[tid] = s;
    }
    __syncthreads();
    const float lv = ls[i];

    float t3d[3]; int t3i[3];
    t3d[0] = t3d[1] = t3d[2] = INFINITY;
    t3i[0] = t3i[1] = t3i[2] = INT_MAX;

    for (int nb = 0; nb < N; nb += CCH) {
        // stage 64 t-rows; accumulate weighted-square partials on the fly
        for (int p = 0; p < CCH; ++p) {
            float v = t[(size_t)(nb + p) * F + tid];
            ts_[p * PAD + tid] = v;
            float e = v * fs[tid];
            e = e * e;
            e += __shfl_xor(e, 1);
            e += __shfl_xor(e, 2);
            e += __shfl_xor(e, 4);
            e += __shfl_xor(e, 8);
            e += __shfl_xor(e, 16);
            e += __shfl_xor(e, 32);
            if (lane == 0) rw[p][wave] = e;
        }
        __syncthreads();
        if (tid < CCH) rsum[tid] = rw[tid][0] + rw[tid][1] + rw[tid][2] + rw[tid][3];
        __syncthreads();

        // dot products: thread (i, c0) handles columns c0 and c0+32.
        // ts_ read: lanes 0..31 -> banks (c0+f)%32 all distinct; lanes 32..63
        // read the same addresses (broadcast). xs read: uniform per half-wave.
        float acc0 = 0.f, acc1 = 0.f;
        #pragma unroll 8
        for (int f = 0; f < F; ++f) {
            float a = xs[i * PAD + f];
            acc0 = fmaf(a, ts_[c0 * PAD + f], acc0);
            acc1 = fmaf(a, ts_[(c0 + 32) * PAD + f], acc1);
        }
        float d0 = sqrtf(lv + rsum[c0])      - 2.0f * acc0;
        float d1 = sqrtf(lv + rsum[c0 + 32]) - 2.0f * acc1;
        insert3(d0, nb + c0,      t3d, t3i);
        insert3(d1, nb + c0 + 32, t3d, t3i);
        __syncthreads();   // before next chunk overwrites ts_
    }

    // merge top-3 across the 32 contiguous lanes sharing row i
    #pragma unroll
    for (int m = 1; m < 32; m <<= 1) {
        float od[3]; int oi[3];
        #pragma unroll
        for (int s = 0; s < 3; ++s) {
            od[s] = __shfl_xor(t3d[s], m);
            oi[s] = __shfl_xor(t3i[s], m);
        }
        merge3(t3d, t3i, od, oi);
    }
    if (c0 == 0) {
        #pragma unroll
        for (int s = 0; s < 3; ++s) {
            int idx = t3i[s];
            idx = idx < 0 ? 0 : (idx >= N ? N - 1 : idx);   // never fault
            out[stashBase + (row0 + i) * 3 + s] = (float)labels[idx];
        }
    }
}

// one-hot rows [0, rowsMain): reads stash, never writes it.
// flat-reshape semantics: out[i] needs stash[i], stash[B+i], stash[2B+i].
__global__ void out_main(float* __restrict__ out, int B, int L,
                         int stashBase, int rowsMain) {
    int tid = blockIdx.x * blockDim.x + threadIdx.x;
    if (tid >= rowsMain * L) return;
    int i = tid / L, c = tid - i * L;
    int s = (int)out[stashBase + i] + (int)out[stashBase + B + i]
          + (int)out[stashBase + 2 * B + i];
    out[tid] = (c == s / 3) ? 1.0f : 0.0f;
}

// single block: buffers the stash slice it needs in LDS, barriers, then
// overwrites the tail cells [rowsMain*L, B*L) (which contain the stash).
__global__ __launch_bounds__(256)
void out_tail(float* __restrict__ out, int B, int L,
              int stashBase, int rowsMain) {
    __shared__ int l0[128], l1[128], l2[128];
    int nt = B - rowsMain;                       // tail rows (62 for B=2048)
    for (int q = threadIdx.x; q < nt * 3; q += 256) {
        int j = q / nt, i = q - j * nt;          // j = which of the 3 slices
        int v = (int)out[stashBase + j * B + rowsMain + i];
        if (j == 0) l0[i] = v; else if (j == 1) l1[i] = v; else l2[i] = v;
    }
    __syncthreads();
    int base = rowsMain * L;
    for (int e = threadIdx.x; e < B * L - base; e += 256) {
        int rr = (base + e) / L - rowsMain, c = (base + e) % L;
        int s = l0[rr] + l1[rr] + l2[rr];
        out[base + e] = (c == s / 3) ? 1.0f : 0.0f;
    }
}

extern "C" void kernel_launch(void* const* d_in, const int* in_sizes, int n_in,
                              void* d_out, int out_size, void* d_ws, size_t ws_size,
                              hipStream_t stream) {
    const float* x      = (const float*)d_in[0];
    const float* t      = (const float*)d_in[1];
    const float* feat   = (const float*)d_in[2];
    const int*   labels = (const int*)d_in[3];
    float*       out    = (float*)d_out;
    const int F = in_sizes[2];           // 256
    const int B = in_sizes[0] / F;       // 2048
    const int N = in_sizes[3];           // 65536
    const int L = out_size / B;          // 100

    const int stashBase = out_size - 3 * B;   // 3B labels stashed in d_out tail
    const int rowsMain  = stashBase / L;      // one-hot rows untouched by stash

    knn_all<<<B / RPB, 256, 0, stream>>>(x, t, feat, labels, out,
                                         F, N, B, stashBase);
    out_main<<<(rowsMain * L + 255) / 256, 256, 0, stream>>>(
        out, B, L, stashBase, rowsMain);
    out_tail<<<1, 256, 0, stream>>>(out, B, L, stashBase, rowsMain);
}

// Round 12
// 4418.840 us; speedup vs baseline: 7.5300x; 7.5277x over previous
//
#include <hip/hip_runtime.h>
#include <math.h>
#include <limits.h>

#define RPB 16     // x-rows per block
#define CCH 32     // train rows per LDS chunk
#define NSPL 8     // N-splits
#define PAD 257    // LDS row stride in floats (bank = (row+f)%32, conflict-free)

// lexicographic (distance, index) compare == jax.lax.top_k stable tie-break
__device__ __forceinline__ bool plt(float da, int ia, float db, int ib) {
    return (da < db) || ((da == db) && (ia < ib));
}

// branchless insert of candidate (d,n) into sorted ascending top-3
__device__ __forceinline__ void insert3(float d, int n, float td[3], int ti[3]) {
    bool b = plt(d, n, td[2], ti[2]);
    float d2 = b ? d : td[2];  int i2 = b ? n : ti[2];
    bool c = plt(d2, i2, td[1], ti[1]);
    float nd1 = c ? d2 : td[1];    int ni1 = c ? i2 : ti[1];
    float nd2 = c ? td[1] : d2;    int ni2 = c ? ti[1] : i2;
    bool e = plt(nd1, ni1, td[0], ti[0]);
    float od0 = td[0]; int oi0 = ti[0];
    td[0] = e ? nd1 : od0;  ti[0] = e ? ni1 : oi0;
    td[1] = e ? od0 : nd1;  ti[1] = e ? oi0 : ni1;
    td[2] = nd2;            ti[2] = ni2;
}

// merge two sorted top-3 lists (b into a), branchless
__device__ __forceinline__ void merge3(float ad[3], int ai[3],
                                       const float bd[3], const int bi[3]) {
    bool b0 = plt(ad[0], ai[0], bd[0], bi[0]);
    float c0d = b0 ? ad[0] : bd[0];  int c0i = b0 ? ai[0] : bi[0];
    float w0d = b0 ? bd[0] : ad[0];  int w0i = b0 ? bi[0] : ai[0];
    bool b1 = plt(ad[1], ai[1], bd[1], bi[1]);
    float m1d = b1 ? ad[1] : bd[1];  int m1i = b1 ? ai[1] : bi[1];
    float M1d = b1 ? bd[1] : ad[1];  int M1i = b1 ? bi[1] : ai[1];
    bool br1 = plt(w0d, w0i, m1d, m1i);
    float r1d = br1 ? w0d : m1d;     int r1i = br1 ? w0i : m1i;
    float t1d = br1 ? m1d : w0d;     int t1i = br1 ? m1i : w0i; // max(w0,m1)
    bool b2 = plt(ad[2], ai[2], bd[2], bi[2]);
    float t2d = b2 ? ad[2] : bd[2];  int t2i = b2 ? ai[2] : bi[2]; // min(a2,b2)
    bool c1 = plt(M1d, M1i, t1d, t1i);
    float ud = c1 ? M1d : t1d;       int ui = c1 ? M1i : t1i;
    bool c2 = plt(ud, ui, t2d, t2i);
    float r2d = c2 ? ud : t2d;       int r2i = c2 ? ui : t2i;
    ad[0] = c0d; ai[0] = c0i;
    ad[1] = r1d; ai[1] = r1i;
    ad[2] = r2d; ai[2] = r2i;
}

// One block = 16 x-rows x one N-slice (N/8 rows).  Scalar loads only,
// named scalar accumulators, 2 insert3 per chunk — green construct class.
// Per (row, split) top-3 (dist + idx-as-float) -> d_out scratch [0, 98304).
__global__ __launch_bounds__(256)
void knn_split(const float* __restrict__ x, const float* __restrict__ t,
               const float* __restrict__ feat, float* __restrict__ outbuf,
               int F, int N, int B) {
    __shared__ float xs[RPB * PAD];    // 16.4 KB
    __shared__ float ts_[CCH * PAD];   // 32.9 KB
    __shared__ float fs[256];
    __shared__ float rsum[CCH];
    __shared__ float ls[RPB];

    const int tid = threadIdx.x;
    const int nRowBlk = B / RPB;                 // 128
    const int rowblk = blockIdx.x & (nRowBlk - 1);
    const int split  = blockIdx.x / nRowBlk;     // 0..NSPL-1
    const int row0 = rowblk * RPB;
    const int nslice = N / NSPL;                 // 8192
    const int nbase = split * nslice;

    // stage 16 x-rows + features (coalesced: f == tid)
    #pragma unroll
    for (int q = 0; q < RPB; ++q)
        xs[q * PAD + tid] = x[(size_t)(row0 + q) * F + tid];
    fs[tid] = feat[tid];
    __syncthreads();

    // left norms (ascending f, one thread per row — one-time cost)
    if (tid < RPB) {
        float s = 0.f;
        for (int f = 0; f < F; ++f) { float v = xs[tid * PAD + f]; s = fmaf(v, v, s); }
        ls[tid] = s;
    }
    __syncthreads();

    const int ipair = tid >> 5;        // 0..7 -> this thread's rows: ipair, ipair+8
    const int c0 = tid & 31;           // column (t-row) within chunk
    const float lvA = ls[ipair];
    const float lvB = ls[ipair + 8];

    float tdA[3], tdB[3]; int tiA[3], tiB[3];
    tdA[0] = tdA[1] = tdA[2] = INFINITY;  tiA[0] = tiA[1] = tiA[2] = INT_MAX;
    tdB[0] = tdB[1] = tdB[2] = INFINITY;  tiB[0] = tiB[1] = tiB[2] = INT_MAX;

    for (int nb = 0; nb < nslice; nb += CCH) {
        // stage chunk: 32 t-rows, fully coalesced (f == tid), no shfl, no branches
        #pragma unroll 4
        for (int q = 0; q < CCH; ++q)
            ts_[q * PAD + tid] = t[(size_t)(nbase + nb + q) * F + tid];
        __syncthreads();

        // right norms: 8 lanes per t-row, strided f = g+8k (parallel pass)
        {
            int r = tid >> 3, g = tid & 7;
            float s = 0.f;
            #pragma unroll 8
            for (int k = 0; k < 32; ++k) {
                float v = ts_[r * PAD + g + 8 * k] * fs[g + 8 * k];
                s = fmaf(v, v, s);
            }
            s += __shfl_xor(s, 1);
            s += __shfl_xor(s, 2);
            s += __shfl_xor(s, 4);
            if (g == 0) rsum[r] = s;
        }
        __syncthreads();

        // dot: this thread's column c0 against rows ipair and ipair+8.
        // ts_ banks (c0+f)%32 distinct over lanes; xs reads broadcast per half-wave.
        float a0 = 0.f, a1 = 0.f;
        #pragma unroll 8
        for (int f = 0; f < F; ++f) {
            float tv = ts_[c0 * PAD + f];
            a0 = fmaf(xs[ipair * PAD + f], tv, a0);
            a1 = fmaf(xs[(ipair + 8) * PAD + f], tv, a1);
        }
        int n = nbase + nb + c0;
        float rv = rsum[c0];
        insert3(sqrtf(lvA + rv) - 2.0f * a0, n, tdA, tiA);
        insert3(sqrtf(lvB + rv) - 2.0f * a1, n, tdB, tiB);
        __syncthreads();   // before next chunk overwrites ts_/rsum
    }

    // merge across the 32 lanes sharing a row (32-aligned half-wave groups)
    #pragma unroll
    for (int m = 1; m < 32; m <<= 1) {
        float od[3]; int oi[3];
        #pragma unroll
        for (int s = 0; s < 3; ++s) { od[s] = __shfl_xor(tdA[s], m); oi[s] = __shfl_xor(tiA[s], m); }
        merge3(tdA, tiA, od, oi);
        #pragma unroll
        for (int s = 0; s < 3; ++s) { od[s] = __shfl_xor(tdB[s], m); oi[s] = __shfl_xor(tiB[s], m); }
        merge3(tdB, tiB, od, oi);
    }
    if (c0 == 0) {
        int rgA = row0 + ipair;
        int rgB = row0 + ipair + 8;
        int baseA = (rgA * NSPL + split) * 6;
        int baseB = (rgB * NSPL + split) * 6;
        #pragma unroll
        for (int s = 0; s < 3; ++s) {
            outbuf[baseA + s]     = tdA[s];
            outbuf[baseA + 3 + s] = (float)tiA[s];   // exact (< 2^24)
            outbuf[baseB + s]     = tdB[s];
            outbuf[baseB + 3 + s] = (float)tiB[s];
        }
    }
}

// Merge NSPL candidate triples per row -> global top-3 -> labels -> stash.
// 256 threads = 32 rows x 8 lanes; shfl merge within 8-aligned groups.
__global__ __launch_bounds__(256)
void knn_merge(float* __restrict__ buf, const int* __restrict__ labels,
               int B, int N, int stashBase) {
    const int tid = threadIdx.x;
    const int row = blockIdx.x * 32 + (tid >> 3);
    const int j = tid & 7;                      // which split (NSPL == 8)
    const int base = (row * NSPL + j) * 6;
    float d[3]; int ii[3];
    #pragma unroll
    for (int s = 0; s < 3; ++s) {
        d[s] = buf[base + s];
        ii[s] = (int)buf[base + 3 + s];
    }
    #pragma unroll
    for (int m = 1; m < 8; m <<= 1) {
        float od[3]; int oi[3];
        #pragma unroll
        for (int s = 0; s < 3; ++s) { od[s] = __shfl_xor(d[s], m); oi[s] = __shfl_xor(ii[s], m); }
        merge3(d, ii, od, oi);
    }
    if (j == 0) {
        #pragma unroll
        for (int s = 0; s < 3; ++s) {
            int idx = ii[s];
            idx = idx < 0 ? 0 : (idx >= N ? N - 1 : idx);   // never fault
            buf[stashBase + row * 3 + s] = (float)labels[idx];
        }
    }
}

// one-hot rows [0, rowsMain): reads stash, never writes it.  (R6/R11-proven)
__global__ void out_main(float* __restrict__ out, int B, int L,
                         int stashBase, int rowsMain) {
    int tid = blockIdx.x * blockDim.x + threadIdx.x;
    if (tid >= rowsMain * L) return;
    int i = tid / L, c = tid - i * L;
    int s = (int)out[stashBase + i] + (int)out[stashBase + B + i]
          + (int)out[stashBase + 2 * B + i];
    out[tid] = (c == s / 3) ? 1.0f : 0.0f;
}

// single block: buffers needed stash into LDS, barriers, overwrites tail. (R6/R11-proven)
__global__ __launch_bounds__(256)
void out_tail(float* __restrict__ out, int B, int L,
              int stashBase, int rowsMain) {
    __shared__ int l0[128], l1[128], l2[128];
    int nt = B - rowsMain;
    for (int q = threadIdx.x; q < nt * 3; q += 256) {
        int j = q / nt, i = q - j * nt;
        int v = (int)out[stashBase + j * B + rowsMain + i];
        if (j == 0) l0[i] = v; else if (j == 1) l1[i] = v; else l2[i] = v;
    }
    __syncthreads();
    int base = rowsMain * L;
    for (int e = threadIdx.x; e < B * L - base; e += 256) {
        int rr = (base + e) / L - rowsMain, c = (base + e) % L;
        int s = l0[rr] + l1[rr] + l2[rr];
        out[base + e] = (c == s / 3) ? 1.0f : 0.0f;
    }
}

extern "C" void kernel_launch(void* const* d_in, const int* in_sizes, int n_in,
                              void* d_out, int out_size, void* d_ws, size_t ws_size,
                              hipStream_t stream) {
    const float* x      = (const float*)d_in[0];
    const float* t      = (const float*)d_in[1];
    const float* feat   = (const float*)d_in[2];
    const int*   labels = (const int*)d_in[3];
    float*       out    = (float*)d_out;
    const int F = in_sizes[2];           // 256
    const int B = in_sizes[0] / F;       // 2048
    const int N = in_sizes[3];           // 65536
    const int L = out_size / B;          // 100

    const int stashBase = out_size - 3 * B;   // 198656
    const int rowsMain  = stashBase / L;      // 1986
    // cand scratch = d_out[0, B*NSPL*6) = [0, 98304) — disjoint from stash

    const int nblk = (B / RPB) * NSPL;        // 1024
    knn_split<<<nblk, 256, 0, stream>>>(x, t, feat, out, F, N, B);
    knn_merge<<<B / 32, 256, 0, stream>>>(out, labels, B, N, stashBase);
    out_main<<<(rowsMain * L + 255) / 256, 256, 0, stream>>>(
        out, B, L, stashBase, rowsMain);
    out_tail<<<1, 256, 0, stream>>>(out, B, L, stashBase, rowsMain);
}

// Round 13
// 2507.544 us; speedup vs baseline: 13.2695x; 1.7622x over previous
//
#include <hip/hip_runtime.h>
#include <math.h>
#include <limits.h>

#define RPB 32     // x-rows per block (2 per thread: rowg, rowg+16)
#define CCH 32     // train rows per LDS chunk (2 per thread: colt, colt+16)
#define NSPL 8     // N-splits
#define PAD 257    // LDS row stride in floats (bank = (row+f)%32)

// lexicographic (distance, index) compare == jax.lax.top_k stable tie-break
__device__ __forceinline__ bool plt(float da, int ia, float db, int ib) {
    return (da < db) || ((da == db) && (ia < ib));
}

// branchless insert of candidate (d,n) into sorted ascending top-3
__device__ __forceinline__ void insert3(float d, int n, float td[3], int ti[3]) {
    bool b = plt(d, n, td[2], ti[2]);
    float d2 = b ? d : td[2];  int i2 = b ? n : ti[2];
    bool c = plt(d2, i2, td[1], ti[1]);
    float nd1 = c ? d2 : td[1];    int ni1 = c ? i2 : ti[1];
    float nd2 = c ? td[1] : d2;    int ni2 = c ? ti[1] : i2;
    bool e = plt(nd1, ni1, td[0], ti[0]);
    float od0 = td[0]; int oi0 = ti[0];
    td[0] = e ? nd1 : od0;  ti[0] = e ? ni1 : oi0;
    td[1] = e ? od0 : nd1;  ti[1] = e ? oi0 : ni1;
    td[2] = nd2;            ti[2] = ni2;
}

// merge two sorted top-3 lists (b into a), branchless
__device__ __forceinline__ void merge3(float ad[3], int ai[3],
                                       const float bd[3], const int bi[3]) {
    bool b0 = plt(ad[0], ai[0], bd[0], bi[0]);
    float c0d = b0 ? ad[0] : bd[0];  int c0i = b0 ? ai[0] : bi[0];
    float w0d = b0 ? bd[0] : ad[0];  int w0i = b0 ? bi[0] : ai[0];
    bool b1 = plt(ad[1], ai[1], bd[1], bi[1]);
    float m1d = b1 ? ad[1] : bd[1];  int m1i = b1 ? ai[1] : bi[1];
    float M1d = b1 ? bd[1] : ad[1];  int M1i = b1 ? bi[1] : ai[1];
    bool br1 = plt(w0d, w0i, m1d, m1i);
    float r1d = br1 ? w0d : m1d;     int r1i = br1 ? w0i : m1i;
    float t1d = br1 ? m1d : w0d;     int t1i = br1 ? m1i : w0i; // max(w0,m1)
    bool b2 = plt(ad[2], ai[2], bd[2], bi[2]);
    float t2d = b2 ? ad[2] : bd[2];  int t2i = b2 ? ai[2] : bi[2]; // min(a2,b2)
    bool c1 = plt(M1d, M1i, t1d, t1i);
    float ud = c1 ? M1d : t1d;       int ui = c1 ? M1i : t1i;
    bool c2 = plt(ud, ui, t2d, t2i);
    float r2d = c2 ? ud : t2d;       int r2i = c2 ? ui : t2i;
    ad[0] = c0d; ai[0] = c0i;
    ad[1] = r1d; ai[1] = r1i;
    ad[2] = r2d; ai[2] = r2i;
}

// One-shot norms: wave per row.  rows [0,N) = weighted t-norms -> rn;
// rows [N, N+B) = unweighted x-norms -> ln.  Scalar loads + shfl tree
// (R6-proven construct class).
__global__ __launch_bounds__(256)
void rnorm_all(const float* __restrict__ t, const float* __restrict__ x,
               const float* __restrict__ feat, float* __restrict__ rn,
               float* __restrict__ ln, int F, int N, int B) {
    int wid  = (blockIdx.x * 256 + threadIdx.x) >> 6;
    int lane = threadIdx.x & 63;
    if (wid >= N + B) return;
    float s = 0.f;
    if (wid < N) {
        #pragma unroll
        for (int k = 0; k < 4; ++k) {
            int f = lane + 64 * k;
            float v = t[(size_t)wid * F + f] * feat[f];
            s = fmaf(v, v, s);
        }
    } else {
        int r = wid - N;
        #pragma unroll
        for (int k = 0; k < 4; ++k) {
            float v = x[(size_t)r * F + lane + 64 * k];
            s = fmaf(v, v, s);
        }
    }
    s += __shfl_xor(s, 1);
    s += __shfl_xor(s, 2);
    s += __shfl_xor(s, 4);
    s += __shfl_xor(s, 8);
    s += __shfl_xor(s, 16);
    s += __shfl_xor(s, 32);
    if (lane == 0) { if (wid < N) rn[wid] = s; else ln[wid - N] = s; }
}

// 2x2 micro-tiled distance + top-3.  Block = 256 thr = 16 row-groups x
// 16 col-threads; thread owns rows (rowg, rowg+16) x cols (colt, colt+16).
// Named scalar accumulators only; scalar LDS reads (broadcast-aligned).
// Norms read from precomputed rn/ln.  Per-(row,split) top-3 -> cand scratch.
__global__ __launch_bounds__(256)
void knn_split2(const float* __restrict__ x, const float* __restrict__ t,
                const float* __restrict__ rn, const float* __restrict__ ln,
                float* __restrict__ outbuf, int F, int N, int B) {
    __shared__ float xs[RPB * PAD];    // 32.9 KB
    __shared__ float ts_[CCH * PAD];   // 32.9 KB

    const int tid = threadIdx.x;
    const int colt = tid & 15;                   // col pair: colt, colt+16
    const int rowg = tid >> 4;                   // row pair: rowg, rowg+16
    const int nRowBlk = B / RPB;                 // 64
    const int rowblk = blockIdx.x & (nRowBlk - 1);
    const int split  = blockIdx.x / nRowBlk;     // 0..NSPL-1
    const int row0 = rowblk * RPB;
    const int nslice = N / NSPL;                 // 8192
    const int nbase = split * nslice;

    // stage 32 x-rows (coalesced: f == tid), once per block
    #pragma unroll
    for (int q = 0; q < RPB; ++q)
        xs[q * PAD + tid] = x[(size_t)(row0 + q) * F + tid];
    __syncthreads();

    const float lvA = ln[row0 + rowg];
    const float lvB = ln[row0 + rowg + 16];

    float tdA[3], tdB[3]; int tiA[3], tiB[3];
    tdA[0] = tdA[1] = tdA[2] = INFINITY;  tiA[0] = tiA[1] = tiA[2] = INT_MAX;
    tdB[0] = tdB[1] = tdB[2] = INFINITY;  tiB[0] = tiB[1] = tiB[2] = INT_MAX;

    for (int nb = 0; nb < nslice; nb += CCH) {
        const int n0 = nbase + nb;
        // stage chunk: 32 t-rows, coalesced (f == tid)
        #pragma unroll 4
        for (int q = 0; q < CCH; ++q)
            ts_[q * PAD + tid] = t[(size_t)(n0 + q) * F + tid];
        __syncthreads();

        const float rvA = rn[n0 + colt];
        const float rvB = rn[n0 + colt + 16];

        // 2x2 dot: ts_ reads = 16 addrs x4 broadcast; xs reads = 4 addrs x16
        float a00 = 0.f, a01 = 0.f, a10 = 0.f, a11 = 0.f;
        #pragma unroll 8
        for (int f = 0; f < F; ++f) {
            float tvA = ts_[colt * PAD + f];
            float tvB = ts_[(colt + 16) * PAD + f];
            float xa = xs[rowg * PAD + f];
            float xb = xs[(rowg + 16) * PAD + f];
            a00 = fmaf(xa, tvA, a00);
            a01 = fmaf(xa, tvB, a01);
            a10 = fmaf(xb, tvA, a10);
            a11 = fmaf(xb, tvB, a11);
        }
        insert3(sqrtf(lvA + rvA) - 2.0f * a00, n0 + colt,      tdA, tiA);
        insert3(sqrtf(lvA + rvB) - 2.0f * a01, n0 + colt + 16, tdA, tiA);
        insert3(sqrtf(lvB + rvA) - 2.0f * a10, n0 + colt,      tdB, tiB);
        insert3(sqrtf(lvB + rvB) - 2.0f * a11, n0 + colt + 16, tdB, tiB);
        __syncthreads();   // before next chunk overwrites ts_
    }

    // merge across the 16 col-threads sharing a row-group (16-aligned lanes)
    #pragma unroll
    for (int m = 1; m < 16; m <<= 1) {
        float od[3]; int oi[3];
        #pragma unroll
        for (int s = 0; s < 3; ++s) { od[s] = __shfl_xor(tdA[s], m); oi[s] = __shfl_xor(tiA[s], m); }
        merge3(tdA, tiA, od, oi);
        #pragma unroll
        for (int s = 0; s < 3; ++s) { od[s] = __shfl_xor(tdB[s], m); oi[s] = __shfl_xor(tiB[s], m); }
        merge3(tdB, tiB, od, oi);
    }
    if (colt == 0) {
        int rgA = row0 + rowg;
        int rgB = row0 + rowg + 16;
        int baseA = (rgA * NSPL + split) * 6;
        int baseB = (rgB * NSPL + split) * 6;
        #pragma unroll
        for (int s = 0; s < 3; ++s) {
            outbuf[baseA + s]     = tdA[s];
            outbuf[baseA + 3 + s] = (float)tiA[s];   // exact (< 2^24)
            outbuf[baseB + s]     = tdB[s];
            outbuf[baseB + 3 + s] = (float)tiB[s];
        }
    }
}

// Merge NSPL candidate triples per row -> global top-3 -> labels -> stash.
// (R12-proven)
__global__ __launch_bounds__(256)
void knn_merge(float* __restrict__ buf, const int* __restrict__ labels,
               int B, int N, int stashBase) {
    const int tid = threadIdx.x;
    const int row = blockIdx.x * 32 + (tid >> 3);
    const int j = tid & 7;                      // which split (NSPL == 8)
    const int base = (row * NSPL + j) * 6;
    float d[3]; int ii[3];
    #pragma unroll
    for (int s = 0; s < 3; ++s) {
        d[s] = buf[base + s];
        ii[s] = (int)buf[base + 3 + s];
    }
    #pragma unroll
    for (int m = 1; m < 8; m <<= 1) {
        float od[3]; int oi[3];
        #pragma unroll
        for (int s = 0; s < 3; ++s) { od[s] = __shfl_xor(d[s], m); oi[s] = __shfl_xor(ii[s], m); }
        merge3(d, ii, od, oi);
    }
    if (j == 0) {
        #pragma unroll
        for (int s = 0; s < 3; ++s) {
            int idx = ii[s];
            idx = idx < 0 ? 0 : (idx >= N ? N - 1 : idx);   // never fault
            buf[stashBase + row * 3 + s] = (float)labels[idx];
        }
    }
}

// one-hot rows [0, rowsMain): reads stash, never writes it.  (R6/R11/R12-proven)
__global__ void out_main(float* __restrict__ out, int B, int L,
                         int stashBase, int rowsMain) {
    int tid = blockIdx.x * blockDim.x + threadIdx.x;
    if (tid >= rowsMain * L) return;
    int i = tid / L, c = tid - i * L;
    int s = (int)out[stashBase + i] + (int)out[stashBase + B + i]
          + (int)out[stashBase + 2 * B + i];
    out[tid] = (c == s / 3) ? 1.0f : 0.0f;
}

// single block: buffers needed stash into LDS, barriers, overwrites tail.
__global__ __launch_bounds__(256)
void out_tail(float* __restrict__ out, int B, int L,
              int stashBase, int rowsMain) {
    __shared__ int l0[128], l1[128], l2[128];
    int nt = B - rowsMain;
    for (int q = threadIdx.x; q < nt * 3; q += 256) {
        int j = q / nt, i = q - j * nt;
        int v = (int)out[stashBase + j * B + rowsMain + i];
        if (j == 0) l0[i] = v; else if (j == 1) l1[i] = v; else l2[i] = v;
    }
    __syncthreads();
    int base = rowsMain * L;
    for (int e = threadIdx.x; e < B * L - base; e += 256) {
        int rr = (base + e) / L - rowsMain, c = (base + e) % L;
        int s = l0[rr] + l1[rr] + l2[rr];
        out[base + e] = (c == s / 3) ? 1.0f : 0.0f;
    }
}

extern "C" void kernel_launch(void* const* d_in, const int* in_sizes, int n_in,
                              void* d_out, int out_size, void* d_ws, size_t ws_size,
                              hipStream_t stream) {
    const float* x      = (const float*)d_in[0];
    const float* t      = (const float*)d_in[1];
    const float* feat   = (const float*)d_in[2];
    const int*   labels = (const int*)d_in[3];
    float*       out    = (float*)d_out;
    const int F = in_sizes[2];           // 256
    const int B = in_sizes[0] / F;       // 2048
    const int N = in_sizes[3];           // 65536
    const int L = out_size / B;          // 100

    const int stashBase = out_size - 3 * B;   // 198656
    const int rowsMain  = stashBase / L;      // 1986
    // scratch layout in d_out (floats):
    //   cand  [0, 98304)          = B*NSPL*6
    //   rn    [98304, 163840)     = N t-norms
    //   ln    [163840, 165888)    = B x-norms
    //   stash [198656, 204800)
    // out_main overwrites [0,198600) only after cand/rn/ln are consumed.
    float* cand = out;
    float* rn   = out + 98304;
    float* ln   = out + 163840;

    const int nrmBlocks = ((N + B) * 64 + 255) / 256;     // wave per row
    rnorm_all<<<nrmBlocks, 256, 0, stream>>>(t, x, feat, rn, ln, F, N, B);

    const int nblk = (B / RPB) * NSPL;        // 512
    knn_split2<<<nblk, 256, 0, stream>>>(x, t, rn, ln, cand, F, N, B);
    knn_merge<<<B / 32, 256, 0, stream>>>(out, labels, B, N, stashBase);
    out_main<<<(rowsMain * L + 255) / 256, 256, 0, stream>>>(
        out, B, L, stashBase, rowsMain);
    out_tail<<<1, 256, 0, stream>>>(out, B, L, stashBase, rowsMain);
}

// Round 14
// 2417.692 us; speedup vs baseline: 13.7626x; 1.0372x over previous
//
#include <hip/hip_runtime.h>
#include <math.h>
#include <limits.h>

#define RPB 64     // x-rows per block (4 per thread: rowg+16k)
#define CCH 64     // train rows per LDS chunk (4 per thread: colt+16k)
#define NSPL 8     // N-splits
#define PAD 257    // LDS row stride in floats (bank = (row+f)%32)

// lexicographic (distance, index) compare == jax.lax.top_k stable tie-break
__device__ __forceinline__ bool plt(float da, int ia, float db, int ib) {
    return (da < db) || ((da == db) && (ia < ib));
}

// branchless insert of candidate (d,n) into sorted ascending top-3
__device__ __forceinline__ void insert3(float d, int n, float td[3], int ti[3]) {
    bool b = plt(d, n, td[2], ti[2]);
    float d2 = b ? d : td[2];  int i2 = b ? n : ti[2];
    bool c = plt(d2, i2, td[1], ti[1]);
    float nd1 = c ? d2 : td[1];    int ni1 = c ? i2 : ti[1];
    float nd2 = c ? td[1] : d2;    int ni2 = c ? ti[1] : i2;
    bool e = plt(nd1, ni1, td[0], ti[0]);
    float od0 = td[0]; int oi0 = ti[0];
    td[0] = e ? nd1 : od0;  ti[0] = e ? ni1 : oi0;
    td[1] = e ? od0 : nd1;  ti[1] = e ? oi0 : ni1;
    td[2] = nd2;            ti[2] = ni2;
}

// merge two sorted top-3 lists (b into a), branchless
__device__ __forceinline__ void merge3(float ad[3], int ai[3],
                                       const float bd[3], const int bi[3]) {
    bool b0 = plt(ad[0], ai[0], bd[0], bi[0]);
    float c0d = b0 ? ad[0] : bd[0];  int c0i = b0 ? ai[0] : bi[0];
    float w0d = b0 ? bd[0] : ad[0];  int w0i = b0 ? bi[0] : ai[0];
    bool b1 = plt(ad[1], ai[1], bd[1], bi[1]);
    float m1d = b1 ? ad[1] : bd[1];  int m1i = b1 ? ai[1] : bi[1];
    float M1d = b1 ? bd[1] : ad[1];  int M1i = b1 ? bi[1] : ai[1];
    bool br1 = plt(w0d, w0i, m1d, m1i);
    float r1d = br1 ? w0d : m1d;     int r1i = br1 ? w0i : m1i;
    float t1d = br1 ? m1d : w0d;     int t1i = br1 ? m1i : w0i; // max(w0,m1)
    bool b2 = plt(ad[2], ai[2], bd[2], bi[2]);
    float t2d = b2 ? ad[2] : bd[2];  int t2i = b2 ? ai[2] : bi[2]; // min(a2,b2)
    bool c1 = plt(M1d, M1i, t1d, t1i);
    float ud = c1 ? M1d : t1d;       int ui = c1 ? M1i : t1i;
    bool c2 = plt(ud, ui, t2d, t2i);
    float r2d = c2 ? ud : t2d;       int r2i = c2 ? ui : t2i;
    ad[0] = c0d; ai[0] = c0i;
    ad[1] = r1d; ai[1] = r1i;
    ad[2] = r2d; ai[2] = r2i;
}

// One-shot norms: wave per row (R13-proven).
__global__ __launch_bounds__(256)
void rnorm_all(const float* __restrict__ t, const float* __restrict__ x,
               const float* __restrict__ feat, float* __restrict__ rn,
               float* __restrict__ ln, int F, int N, int B) {
    int wid  = (blockIdx.x * 256 + threadIdx.x) >> 6;
    int lane = threadIdx.x & 63;
    if (wid >= N + B) return;
    float s = 0.f;
    if (wid < N) {
        #pragma unroll
        for (int k = 0; k < 4; ++k) {
            int f = lane + 64 * k;
            float v = t[(size_t)wid * F + f] * feat[f];
            s = fmaf(v, v, s);
        }
    } else {
        int r = wid - N;
        #pragma unroll
        for (int k = 0; k < 4; ++k) {
            float v = x[(size_t)r * F + lane + 64 * k];
            s = fmaf(v, v, s);
        }
    }
    s += __shfl_xor(s, 1);
    s += __shfl_xor(s, 2);
    s += __shfl_xor(s, 4);
    s += __shfl_xor(s, 8);
    s += __shfl_xor(s, 16);
    s += __shfl_xor(s, 32);
    if (lane == 0) { if (wid < N) rn[wid] = s; else ln[wid - N] = s; }
}

// 4x4 micro-tiled distance + top-3.  256 thr = 16 rowg x 16 colt; thread
// owns rows {rowg+16k} x cols {colt+16k}, k=0..3.  16 named accumulators,
// scalar LDS reads only (broadcast-aligned, conflict-free), outer loops
// unroll-pinned.  Norms from rn/ln.  Per-(row,split) top-3 -> cand scratch.
__global__ __launch_bounds__(256)
void knn_split4(const float* __restrict__ x, const float* __restrict__ t,
                const float* __restrict__ rn, const float* __restrict__ ln,
                float* __restrict__ outbuf, int F, int N, int B) {
    __shared__ float xs[RPB * PAD];    // 65.8 KB
    __shared__ float ts_[CCH * PAD];   // 65.8 KB  (131.6 KB total, 1 block/CU)

    const int tid = threadIdx.x;
    const int colt = tid & 15;
    const int rowg = tid >> 4;
    const int nRowBlk = B / RPB;                 // 32
    const int rowblk = blockIdx.x & (nRowBlk - 1);
    const int split  = blockIdx.x / nRowBlk;     // 0..NSPL-1
    const int row0 = rowblk * RPB;
    const int nslice = N / NSPL;                 // 8192
    const int nbase = split * nslice;

    // stage 64 x-rows (coalesced: f == tid), once per block
    #pragma unroll 4
    for (int q = 0; q < RPB; ++q)
        xs[q * PAD + tid] = x[(size_t)(row0 + q) * F + tid];
    __syncthreads();

    const float lvA = ln[row0 + rowg];
    const float lvB = ln[row0 + rowg + 16];
    const float lvC = ln[row0 + rowg + 32];
    const float lvD = ln[row0 + rowg + 48];

    float tdA[3], tdB[3], tdC[3], tdD[3];
    int   tiA[3], tiB[3], tiC[3], tiD[3];
    tdA[0]=tdA[1]=tdA[2]=INFINITY; tiA[0]=tiA[1]=tiA[2]=INT_MAX;
    tdB[0]=tdB[1]=tdB[2]=INFINITY; tiB[0]=tiB[1]=tiB[2]=INT_MAX;
    tdC[0]=tdC[1]=tdC[2]=INFINITY; tiC[0]=tiC[1]=tiC[2]=INT_MAX;
    tdD[0]=tdD[1]=tdD[2]=INFINITY; tiD[0]=tiD[1]=tiD[2]=INT_MAX;

    #pragma unroll 1
    for (int nb = 0; nb < nslice; nb += CCH) {
        const int n0 = nbase + nb;
        // stage chunk: 64 t-rows, coalesced (f == tid)
        #pragma unroll 4
        for (int q = 0; q < CCH; ++q)
            ts_[q * PAD + tid] = t[(size_t)(n0 + q) * F + tid];
        __syncthreads();

        const float rv0 = rn[n0 + colt];
        const float rv1 = rn[n0 + colt + 16];
        const float rv2 = rn[n0 + colt + 32];
        const float rv3 = rn[n0 + colt + 48];

        // 4x4 dot: 8 scalar LDS reads -> 16 FMA per f (0.5 reads/FMA)
        float a00=0.f,a01=0.f,a02=0.f,a03=0.f;
        float a10=0.f,a11=0.f,a12=0.f,a13=0.f;
        float a20=0.f,a21=0.f,a22=0.f,a23=0.f;
        float a30=0.f,a31=0.f,a32=0.f,a33=0.f;
        #pragma unroll 4
        for (int f = 0; f < F; ++f) {
            float t0 = ts_[colt * PAD + f];
            float t1 = ts_[(colt + 16) * PAD + f];
            float t2 = ts_[(colt + 32) * PAD + f];
            float t3 = ts_[(colt + 48) * PAD + f];
            float x0 = xs[rowg * PAD + f];
            float x1 = xs[(rowg + 16) * PAD + f];
            float x2 = xs[(rowg + 32) * PAD + f];
            float x3 = xs[(rowg + 48) * PAD + f];
            a00 = fmaf(x0, t0, a00); a01 = fmaf(x0, t1, a01);
            a02 = fmaf(x0, t2, a02); a03 = fmaf(x0, t3, a03);
            a10 = fmaf(x1, t0, a10); a11 = fmaf(x1, t1, a11);
            a12 = fmaf(x1, t2, a12); a13 = fmaf(x1, t3, a13);
            a20 = fmaf(x2, t0, a20); a21 = fmaf(x2, t1, a21);
            a22 = fmaf(x2, t2, a22); a23 = fmaf(x2, t3, a23);
            a30 = fmaf(x3, t0, a30); a31 = fmaf(x3, t1, a31);
            a32 = fmaf(x3, t2, a32); a33 = fmaf(x3, t3, a33);
        }
        const int nc0 = n0 + colt, nc1 = n0 + colt + 16,
                  nc2 = n0 + colt + 32, nc3 = n0 + colt + 48;
        insert3(sqrtf(lvA + rv0) - 2.0f * a00, nc0, tdA, tiA);
        insert3(sqrtf(lvA + rv1) - 2.0f * a01, nc1, tdA, tiA);
        insert3(sqrtf(lvA + rv2) - 2.0f * a02, nc2, tdA, tiA);
        insert3(sqrtf(lvA + rv3) - 2.0f * a03, nc3, tdA, tiA);
        insert3(sqrtf(lvB + rv0) - 2.0f * a10, nc0, tdB, tiB);
        insert3(sqrtf(lvB + rv1) - 2.0f * a11, nc1, tdB, tiB);
        insert3(sqrtf(lvB + rv2) - 2.0f * a12, nc2, tdB, tiB);
        insert3(sqrtf(lvB + rv3) - 2.0f * a13, nc3, tdB, tiB);
        insert3(sqrtf(lvC + rv0) - 2.0f * a20, nc0, tdC, tiC);
        insert3(sqrtf(lvC + rv1) - 2.0f * a21, nc1, tdC, tiC);
        insert3(sqrtf(lvC + rv2) - 2.0f * a22, nc2, tdC, tiC);
        insert3(sqrtf(lvC + rv3) - 2.0f * a23, nc3, tdC, tiC);
        insert3(sqrtf(lvD + rv0) - 2.0f * a30, nc0, tdD, tiD);
        insert3(sqrtf(lvD + rv1) - 2.0f * a31, nc1, tdD, tiD);
        insert3(sqrtf(lvD + rv2) - 2.0f * a32, nc2, tdD, tiD);
        insert3(sqrtf(lvD + rv3) - 2.0f * a33, nc3, tdD, tiD);
        __syncthreads();   // before next chunk overwrites ts_
    }

    // merge across the 16 colt threads sharing a row-group (16-aligned lanes)
    #pragma unroll 1
    for (int m = 1; m < 16; m <<= 1) {
        float od[3]; int oi[3];
        #pragma unroll
        for (int s = 0; s < 3; ++s) { od[s] = __shfl_xor(tdA[s], m); oi[s] = __shfl_xor(tiA[s], m); }
        merge3(tdA, tiA, od, oi);
        #pragma unroll
        for (int s = 0; s < 3; ++s) { od[s] = __shfl_xor(tdB[s], m); oi[s] = __shfl_xor(tiB[s], m); }
        merge3(tdB, tiB, od, oi);
        #pragma unroll
        for (int s = 0; s < 3; ++s) { od[s] = __shfl_xor(tdC[s], m); oi[s] = __shfl_xor(tiC[s], m); }
        merge3(tdC, tiC, od, oi);
        #pragma unroll
        for (int s = 0; s < 3; ++s) { od[s] = __shfl_xor(tdD[s], m); oi[s] = __shfl_xor(tiD[s], m); }
        merge3(tdD, tiD, od, oi);
    }
    if (colt == 0) {
        int baseA = ((row0 + rowg)      * NSPL + split) * 6;
        int baseB = ((row0 + rowg + 16) * NSPL + split) * 6;
        int baseC = ((row0 + rowg + 32) * NSPL + split) * 6;
        int baseD = ((row0 + rowg + 48) * NSPL + split) * 6;
        #pragma unroll
        for (int s = 0; s < 3; ++s) {
            outbuf[baseA + s] = tdA[s];  outbuf[baseA + 3 + s] = (float)tiA[s];
            outbuf[baseB + s] = tdB[s];  outbuf[baseB + 3 + s] = (float)tiB[s];
            outbuf[baseC + s] = tdC[s];  outbuf[baseC + 3 + s] = (float)tiC[s];
            outbuf[baseD + s] = tdD[s];  outbuf[baseD + 3 + s] = (float)tiD[s];
        }
    }
}

// Merge NSPL candidate triples per row -> global top-3 -> labels -> stash.
// (R12/R13-proven)
__global__ __launch_bounds__(256)
void knn_merge(float* __restrict__ buf, const int* __restrict__ labels,
               int B, int N, int stashBase) {
    const int tid = threadIdx.x;
    const int row = blockIdx.x * 32 + (tid >> 3);
    const int j = tid & 7;                      // which split (NSPL == 8)
    const int base = (row * NSPL + j) * 6;
    float d[3]; int ii[3];
    #pragma unroll
    for (int s = 0; s < 3; ++s) {
        d[s] = buf[base + s];
        ii[s] = (int)buf[base + 3 + s];
    }
    #pragma unroll
    for (int m = 1; m < 8; m <<= 1) {
        float od[3]; int oi[3];
        #pragma unroll
        for (int s = 0; s < 3; ++s) { od[s] = __shfl_xor(d[s], m); oi[s] = __shfl_xor(ii[s], m); }
        merge3(d, ii, od, oi);
    }
    if (j == 0) {
        #pragma unroll
        for (int s = 0; s < 3; ++s) {
            int idx = ii[s];
            idx = idx < 0 ? 0 : (idx >= N ? N - 1 : idx);   // never fault
            buf[stashBase + row * 3 + s] = (float)labels[idx];
        }
    }
}

// one-hot rows [0, rowsMain): reads stash, never writes it.  (proven)
__global__ void out_main(float* __restrict__ out, int B, int L,
                         int stashBase, int rowsMain) {
    int tid = blockIdx.x * blockDim.x + threadIdx.x;
    if (tid >= rowsMain * L) return;
    int i = tid / L, c = tid - i * L;
    int s = (int)out[stashBase + i] + (int)out[stashBase + B + i]
          + (int)out[stashBase + 2 * B + i];
    out[tid] = (c == s / 3) ? 1.0f : 0.0f;
}

// single block: buffers needed stash into LDS, barriers, overwrites tail. (proven)
__global__ __launch_bounds__(256)
void out_tail(float* __restrict__ out, int B, int L,
              int stashBase, int rowsMain) {
    __shared__ int l0[128], l1[128], l2[128];
    int nt = B - rowsMain;
    for (int q = threadIdx.x; q < nt * 3; q += 256) {
        int j = q / nt, i = q - j * nt;
        int v = (int)out[stashBase + j * B + rowsMain + i];
        if (j == 0) l0[i] = v; else if (j == 1) l1[i] = v; else l2[i] = v;
    }
    __syncthreads();
    int base = rowsMain * L;
    for (int e = threadIdx.x; e < B * L - base; e += 256) {
        int rr = (base + e) / L - rowsMain, c = (base + e) % L;
        int s = l0[rr] + l1[rr] + l2[rr];
        out[base + e] = (c == s / 3) ? 1.0f : 0.0f;
    }
}

extern "C" void kernel_launch(void* const* d_in, const int* in_sizes, int n_in,
                              void* d_out, int out_size, void* d_ws, size_t ws_size,
                              hipStream_t stream) {
    const float* x      = (const float*)d_in[0];
    const float* t      = (const float*)d_in[1];
    const float* feat   = (const float*)d_in[2];
    const int*   labels = (const int*)d_in[3];
    float*       out    = (float*)d_out;
    const int F = in_sizes[2];           // 256
    const int B = in_sizes[0] / F;       // 2048
    const int N = in_sizes[3];           // 65536
    const int L = out_size / B;          // 100

    const int stashBase = out_size - 3 * B;   // 198656
    const int rowsMain  = stashBase / L;      // 1986
    // scratch layout in d_out (floats):
    //   cand  [0, 98304) ; rn [98304, 163840) ; ln [163840, 165888)
    //   stash [198656, 204800)
    float* cand = out;
    float* rn   = out + 98304;
    float* ln   = out + 163840;

    const int nrmBlocks = ((N + B) * 64 + 255) / 256;     // wave per row
    rnorm_all<<<nrmBlocks, 256, 0, stream>>>(t, x, feat, rn, ln, F, N, B);

    const int nblk = (B / RPB) * NSPL;        // 256 (1 block/CU)
    knn_split4<<<nblk, 256, 0, stream>>>(x, t, rn, ln, cand, F, N, B);
    knn_merge<<<B / 32, 256, 0, stream>>>(out, labels, B, N, stashBase);
    out_main<<<(rowsMain * L + 255) / 256, 256, 0, stream>>>(
        out, B, L, stashBase, rowsMain);
    out_tail<<<1, 256, 0, stream>>>(out, B, L, stashBase, rowsMain);
}

// Round 15
// 2171.184 us; speedup vs baseline: 15.3252x; 1.1135x over previous
//
#include <hip/hip_runtime.h>
#include <math.h>
#include <limits.h>

#define RPB 64     // x-rows per block (4 per thread: rowg+16k)
#define CCH 64     // train rows per LDS chunk (4 per thread: colt+16k)
#define NSPL 8     // N-splits
#define PAD 258    // LDS row stride in floats (even -> 8B-aligned float2 reads)

// lexicographic (distance, index) compare == jax.lax.top_k stable tie-break
__device__ __forceinline__ bool plt(float da, int ia, float db, int ib) {
    return (da < db) || ((da == db) && (ia < ib));
}

// branchless insert of candidate (d,n) into sorted ascending top-3
__device__ __forceinline__ void insert3(float d, int n, float td[3], int ti[3]) {
    bool b = plt(d, n, td[2], ti[2]);
    float d2 = b ? d : td[2];  int i2 = b ? n : ti[2];
    bool c = plt(d2, i2, td[1], ti[1]);
    float nd1 = c ? d2 : td[1];    int ni1 = c ? i2 : ti[1];
    float nd2 = c ? td[1] : d2;    int ni2 = c ? ti[1] : i2;
    bool e = plt(nd1, ni1, td[0], ti[0]);
    float od0 = td[0]; int oi0 = ti[0];
    td[0] = e ? nd1 : od0;  ti[0] = e ? ni1 : oi0;
    td[1] = e ? od0 : nd1;  ti[1] = e ? oi0 : ni1;
    td[2] = nd2;            ti[2] = ni2;
}

// merge two sorted top-3 lists (b into a), branchless
__device__ __forceinline__ void merge3(float ad[3], int ai[3],
                                       const float bd[3], const int bi[3]) {
    bool b0 = plt(ad[0], ai[0], bd[0], bi[0]);
    float c0d = b0 ? ad[0] : bd[0];  int c0i = b0 ? ai[0] : bi[0];
    float w0d = b0 ? bd[0] : ad[0];  int w0i = b0 ? bi[0] : ai[0];
    bool b1 = plt(ad[1], ai[1], bd[1], bi[1]);
    float m1d = b1 ? ad[1] : bd[1];  int m1i = b1 ? ai[1] : bi[1];
    float M1d = b1 ? bd[1] : ad[1];  int M1i = b1 ? bi[1] : ai[1];
    bool br1 = plt(w0d, w0i, m1d, m1i);
    float r1d = br1 ? w0d : m1d;     int r1i = br1 ? w0i : m1i;
    float t1d = br1 ? m1d : w0d;     int t1i = br1 ? m1i : w0i; // max(w0,m1)
    bool b2 = plt(ad[2], ai[2], bd[2], bi[2]);
    float t2d = b2 ? ad[2] : bd[2];  int t2i = b2 ? ai[2] : bi[2]; // min(a2,b2)
    bool c1 = plt(M1d, M1i, t1d, t1i);
    float ud = c1 ? M1d : t1d;       int ui = c1 ? M1i : t1i;
    bool c2 = plt(ud, ui, t2d, t2i);
    float r2d = c2 ? ud : t2d;       int r2i = c2 ? ui : t2i;
    ad[0] = c0d; ai[0] = c0i;
    ad[1] = r1d; ai[1] = r1i;
    ad[2] = r2d; ai[2] = r2i;
}

// One-shot norms: wave per row (R13-proven).
__global__ __launch_bounds__(256)
void rnorm_all(const float* __restrict__ t, const float* __restrict__ x,
               const float* __restrict__ feat, float* __restrict__ rn,
               float* __restrict__ ln, int F, int N, int B) {
    int wid  = (blockIdx.x * 256 + threadIdx.x) >> 6;
    int lane = threadIdx.x & 63;
    if (wid >= N + B) return;
    float s = 0.f;
    if (wid < N) {
        #pragma unroll
        for (int k = 0; k < 4; ++k) {
            int f = lane + 64 * k;
            float v = t[(size_t)wid * F + f] * feat[f];
            s = fmaf(v, v, s);
        }
    } else {
        int r = wid - N;
        #pragma unroll
        for (int k = 0; k < 4; ++k) {
            float v = x[(size_t)r * F + lane + 64 * k];
            s = fmaf(v, v, s);
        }
    }
    s += __shfl_xor(s, 1);
    s += __shfl_xor(s, 2);
    s += __shfl_xor(s, 4);
    s += __shfl_xor(s, 8);
    s += __shfl_xor(s, 16);
    s += __shfl_xor(s, 32);
    if (lane == 0) { if (wid < N) rn[wid] = s; else ln[wid - N] = s; }
}

// 4x4 micro-tiled distance + top-3 with float2 (b64) LDS reads over f.
// 256 thr = 16 rowg x 16 colt; thread owns rows {rowg+16k} x cols {colt+16k}.
// 16 named accumulators; all LDS reads broadcast-aligned conflict-free.
__global__ __launch_bounds__(256)
void knn_split4(const float* __restrict__ x, const float* __restrict__ t,
                const float* __restrict__ rn, const float* __restrict__ ln,
                float* __restrict__ outbuf, int F, int N, int B) {
    __shared__ float xs[RPB * PAD];    // 66.0 KB
    __shared__ float ts_[CCH * PAD];   // 66.0 KB  (132 KB total, 1 block/CU)

    const int tid = threadIdx.x;
    const int colt = tid & 15;
    const int rowg = tid >> 4;
    const int nRowBlk = B / RPB;                 // 32
    const int rowblk = blockIdx.x & (nRowBlk - 1);
    const int split  = blockIdx.x / nRowBlk;     // 0..NSPL-1
    const int row0 = rowblk * RPB;
    const int nslice = N / NSPL;                 // 8192
    const int nbase = split * nslice;

    // stage 64 x-rows (coalesced: f == tid), once per block
    #pragma unroll 4
    for (int q = 0; q < RPB; ++q)
        xs[q * PAD + tid] = x[(size_t)(row0 + q) * F + tid];
    __syncthreads();

    const float lvA = ln[row0 + rowg];
    const float lvB = ln[row0 + rowg + 16];
    const float lvC = ln[row0 + rowg + 32];
    const float lvD = ln[row0 + rowg + 48];

    float tdA[3], tdB[3], tdC[3], tdD[3];
    int   tiA[3], tiB[3], tiC[3], tiD[3];
    tdA[0]=tdA[1]=tdA[2]=INFINITY; tiA[0]=tiA[1]=tiA[2]=INT_MAX;
    tdB[0]=tdB[1]=tdB[2]=INFINITY; tiB[0]=tiB[1]=tiB[2]=INT_MAX;
    tdC[0]=tdC[1]=tdC[2]=INFINITY; tiC[0]=tiC[1]=tiC[2]=INT_MAX;
    tdD[0]=tdD[1]=tdD[2]=INFINITY; tiD[0]=tiD[1]=tiD[2]=INT_MAX;

    #pragma unroll 1
    for (int nb = 0; nb < nslice; nb += CCH) {
        const int n0 = nbase + nb;
        // stage chunk: 64 t-rows, coalesced (f == tid)
        #pragma unroll 4
        for (int q = 0; q < CCH; ++q)
            ts_[q * PAD + tid] = t[(size_t)(n0 + q) * F + tid];
        __syncthreads();

        const float rv0 = rn[n0 + colt];
        const float rv1 = rn[n0 + colt + 16];
        const float rv2 = rn[n0 + colt + 32];
        const float rv3 = rn[n0 + colt + 48];

        // 4x4 dot, 2 f per iter: 8 ds_read_b64 -> 32 FMA (0.25 instr/FMA)
        float a00=0.f,a01=0.f,a02=0.f,a03=0.f;
        float a10=0.f,a11=0.f,a12=0.f,a13=0.f;
        float a20=0.f,a21=0.f,a22=0.f,a23=0.f;
        float a30=0.f,a31=0.f,a32=0.f,a33=0.f;
        #pragma unroll 4
        for (int f = 0; f < F; f += 2) {
            float2 t0 = *(const float2*)&ts_[colt * PAD + f];
            float2 t1 = *(const float2*)&ts_[(colt + 16) * PAD + f];
            float2 t2 = *(const float2*)&ts_[(colt + 32) * PAD + f];
            float2 t3 = *(const float2*)&ts_[(colt + 48) * PAD + f];
            float2 x0 = *(const float2*)&xs[rowg * PAD + f];
            float2 x1 = *(const float2*)&xs[(rowg + 16) * PAD + f];
            float2 x2 = *(const float2*)&xs[(rowg + 32) * PAD + f];
            float2 x3 = *(const float2*)&xs[(rowg + 48) * PAD + f];
            a00 = fmaf(x0.x, t0.x, a00); a00 = fmaf(x0.y, t0.y, a00);
            a01 = fmaf(x0.x, t1.x, a01); a01 = fmaf(x0.y, t1.y, a01);
            a02 = fmaf(x0.x, t2.x, a02); a02 = fmaf(x0.y, t2.y, a02);
            a03 = fmaf(x0.x, t3.x, a03); a03 = fmaf(x0.y, t3.y, a03);
            a10 = fmaf(x1.x, t0.x, a10); a10 = fmaf(x1.y, t0.y, a10);
            a11 = fmaf(x1.x, t1.x, a11); a11 = fmaf(x1.y, t1.y, a11);
            a12 = fmaf(x1.x, t2.x, a12); a12 = fmaf(x1.y, t2.y, a12);
            a13 = fmaf(x1.x, t3.x, a13); a13 = fmaf(x1.y, t3.y, a13);
            a20 = fmaf(x2.x, t0.x, a20); a20 = fmaf(x2.y, t0.y, a20);
            a21 = fmaf(x2.x, t1.x, a21); a21 = fmaf(x2.y, t1.y, a21);
            a22 = fmaf(x2.x, t2.x, a22); a22 = fmaf(x2.y, t2.y, a22);
            a23 = fmaf(x2.x, t3.x, a23); a23 = fmaf(x2.y, t3.y, a23);
            a30 = fmaf(x3.x, t0.x, a30); a30 = fmaf(x3.y, t0.y, a30);
            a31 = fmaf(x3.x, t1.x, a31); a31 = fmaf(x3.y, t1.y, a31);
            a32 = fmaf(x3.x, t2.x, a32); a32 = fmaf(x3.y, t2.y, a32);
            a33 = fmaf(x3.x, t3.x, a33); a33 = fmaf(x3.y, t3.y, a33);
        }
        const int nc0 = n0 + colt, nc1 = n0 + colt + 16,
                  nc2 = n0 + colt + 32, nc3 = n0 + colt + 48;
        insert3(sqrtf(lvA + rv0) - 2.0f * a00, nc0, tdA, tiA);
        insert3(sqrtf(lvA + rv1) - 2.0f * a01, nc1, tdA, tiA);
        insert3(sqrtf(lvA + rv2) - 2.0f * a02, nc2, tdA, tiA);
        insert3(sqrtf(lvA + rv3) - 2.0f * a03, nc3, tdA, tiA);
        insert3(sqrtf(lvB + rv0) - 2.0f * a10, nc0, tdB, tiB);
        insert3(sqrtf(lvB + rv1) - 2.0f * a11, nc1, tdB, tiB);
        insert3(sqrtf(lvB + rv2) - 2.0f * a12, nc2, tdB, tiB);
        insert3(sqrtf(lvB + rv3) - 2.0f * a13, nc3, tdB, tiB);
        insert3(sqrtf(lvC + rv0) - 2.0f * a20, nc0, tdC, tiC);
        insert3(sqrtf(lvC + rv1) - 2.0f * a21, nc1, tdC, tiC);
        insert3(sqrtf(lvC + rv2) - 2.0f * a22, nc2, tdC, tiC);
        insert3(sqrtf(lvC + rv3) - 2.0f * a23, nc3, tdC, tiC);
        insert3(sqrtf(lvD + rv0) - 2.0f * a30, nc0, tdD, tiD);
        insert3(sqrtf(lvD + rv1) - 2.0f * a31, nc1, tdD, tiD);
        insert3(sqrtf(lvD + rv2) - 2.0f * a32, nc2, tdD, tiD);
        insert3(sqrtf(lvD + rv3) - 2.0f * a33, nc3, tdD, tiD);
        __syncthreads();   // before next chunk overwrites ts_
    }

    // merge across the 16 colt threads sharing a row-group (16-aligned lanes)
    #pragma unroll 1
    for (int m = 1; m < 16; m <<= 1) {
        float od[3]; int oi[3];
        #pragma unroll
        for (int s = 0; s < 3; ++s) { od[s] = __shfl_xor(tdA[s], m); oi[s] = __shfl_xor(tiA[s], m); }
        merge3(tdA, tiA, od, oi);
        #pragma unroll
        for (int s = 0; s < 3; ++s) { od[s] = __shfl_xor(tdB[s], m); oi[s] = __shfl_xor(tiB[s], m); }
        merge3(tdB, tiB, od, oi);
        #pragma unroll
        for (int s = 0; s < 3; ++s) { od[s] = __shfl_xor(tdC[s], m); oi[s] = __shfl_xor(tiC[s], m); }
        merge3(tdC, tiC, od, oi);
        #pragma unroll
        for (int s = 0; s < 3; ++s) { od[s] = __shfl_xor(tdD[s], m); oi[s] = __shfl_xor(tiD[s], m); }
        merge3(tdD, tiD, od, oi);
    }
    if (colt == 0) {
        int baseA = ((row0 + rowg)      * NSPL + split) * 6;
        int baseB = ((row0 + rowg + 16) * NSPL + split) * 6;
        int baseC = ((row0 + rowg + 32) * NSPL + split) * 6;
        int baseD = ((row0 + rowg + 48) * NSPL + split) * 6;
        #pragma unroll
        for (int s = 0; s < 3; ++s) {
            outbuf[baseA + s] = tdA[s];  outbuf[baseA + 3 + s] = (float)tiA[s];
            outbuf[baseB + s] = tdB[s];  outbuf[baseB + 3 + s] = (float)tiB[s];
            outbuf[baseC + s] = tdC[s];  outbuf[baseC + 3 + s] = (float)tiC[s];
            outbuf[baseD + s] = tdD[s];  outbuf[baseD + 3 + s] = (float)tiD[s];
        }
    }
}

// Merge NSPL candidate triples per row -> global top-3 -> labels -> stash.
__global__ __launch_bounds__(256)
void knn_merge(float* __restrict__ buf, const int* __restrict__ labels,
               int B, int N, int stashBase) {
    const int tid = threadIdx.x;
    const int row = blockIdx.x * 32 + (tid >> 3);
    const int j = tid & 7;                      // which split (NSPL == 8)
    const int base = (row * NSPL + j) * 6;
    float d[3]; int ii[3];
    #pragma unroll
    for (int s = 0; s < 3; ++s) {
        d[s] = buf[base + s];
        ii[s] = (int)buf[base + 3 + s];
    }
    #pragma unroll
    for (int m = 1; m < 8; m <<= 1) {
        float od[3]; int oi[3];
        #pragma unroll
        for (int s = 0; s < 3; ++s) { od[s] = __shfl_xor(d[s], m); oi[s] = __shfl_xor(ii[s], m); }
        merge3(d, ii, od, oi);
    }
    if (j == 0) {
        #pragma unroll
        for (int s = 0; s < 3; ++s) {
            int idx = ii[s];
            idx = idx < 0 ? 0 : (idx >= N ? N - 1 : idx);   // never fault
            buf[stashBase + row * 3 + s] = (float)labels[idx];
        }
    }
}

// one-hot rows [0, rowsMain): reads stash, never writes it.  (proven)
__global__ void out_main(float* __restrict__ out, int B, int L,
                         int stashBase, int rowsMain) {
    int tid = blockIdx.x * blockDim.x + threadIdx.x;
    if (tid >= rowsMain * L) return;
    int i = tid / L, c = tid - i * L;
    int s = (int)out[stashBase + i] + (int)out[stashBase + B + i]
          + (int)out[stashBase + 2 * B + i];
    out[tid] = (c == s / 3) ? 1.0f : 0.0f;
}

// single block: buffers needed stash into LDS, barriers, overwrites tail. (proven)
__global__ __launch_bounds__(256)
void out_tail(float* __restrict__ out, int B, int L,
              int stashBase, int rowsMain) {
    __shared__ int l0[128], l1[128], l2[128];
    int nt = B - rowsMain;
    for (int q = threadIdx.x; q < nt * 3; q += 256) {
        int j = q / nt, i = q - j * nt;
        int v = (int)out[stashBase + j * B + rowsMain + i];
        if (j == 0) l0[i] = v; else if (j == 1) l1[i] = v; else l2[i] = v;
    }
    __syncthreads();
    int base = rowsMain * L;
    for (int e = threadIdx.x; e < B * L - base; e += 256) {
        int rr = (base + e) / L - rowsMain, c = (base + e) % L;
        int s = l0[rr] + l1[rr] + l2[rr];
        out[base + e] = (c == s / 3) ? 1.0f : 0.0f;
    }
}

extern "C" void kernel_launch(void* const* d_in, const int* in_sizes, int n_in,
                              void* d_out, int out_size, void* d_ws, size_t ws_size,
                              hipStream_t stream) {
    const float* x      = (const float*)d_in[0];
    const float* t      = (const float*)d_in[1];
    const float* feat   = (const float*)d_in[2];
    const int*   labels = (const int*)d_in[3];
    float*       out    = (float*)d_out;
    const int F = in_sizes[2];           // 256
    const int B = in_sizes[0] / F;       // 2048
    const int N = in_sizes[3];           // 65536
    const int L = out_size / B;          // 100

    const int stashBase = out_size - 3 * B;   // 198656
    const int rowsMain  = stashBase / L;      // 1986
    // scratch layout in d_out (floats):
    //   cand  [0, 98304) ; rn [98304, 163840) ; ln [163840, 165888)
    //   stash [198656, 204800)
    float* cand = out;
    float* rn   = out + 98304;
    float* ln   = out + 163840;

    const int nrmBlocks = ((N + B) * 64 + 255) / 256;     // wave per row
    rnorm_all<<<nrmBlocks, 256, 0, stream>>>(t, x, feat, rn, ln, F, N, B);

    const int nblk = (B / RPB) * NSPL;        // 256 (1 block/CU)
    knn_split4<<<nblk, 256, 0, stream>>>(x, t, rn, ln, cand, F, N, B);
    knn_merge<<<B / 32, 256, 0, stream>>>(out, labels, B, N, stashBase);
    out_main<<<(rowsMain * L + 255) / 256, 256, 0, stream>>>(
        out, B, L, stashBase, rowsMain);
    out_tail<<<1, 256, 0, stream>>>(out, B, L, stashBase, rowsMain);
}

// Round 16
// 1655.029 us; speedup vs baseline: 20.1047x; 1.3119x over previous
//
#include <hip/hip_runtime.h>
#include <math.h>
#include <limits.h>

#define RPB 64     // x-rows per block
#define CCH 64     // train cols per chunk
#define KF  128    // f per K-chunk (2 chunks cover F=256)
#define NSPL 16    // N-splits (grid = 32 rowblk x 16 = 512 blocks)
#define PAD 130    // LDS row stride in floats (even -> 8B-aligned float2)

// lexicographic (distance, index) compare == jax.lax.top_k stable tie-break
__device__ __forceinline__ bool plt(float da, int ia, float db, int ib) {
    return (da < db) || ((da == db) && (ia < ib));
}

// branchless insert of candidate (d,n) into sorted ascending top-3
__device__ __forceinline__ void insert3(float d, int n, float td[3], int ti[3]) {
    bool b = plt(d, n, td[2], ti[2]);
    float d2 = b ? d : td[2];  int i2 = b ? n : ti[2];
    bool c = plt(d2, i2, td[1], ti[1]);
    float nd1 = c ? d2 : td[1];    int ni1 = c ? i2 : ti[1];
    float nd2 = c ? td[1] : d2;    int ni2 = c ? ti[1] : i2;
    bool e = plt(nd1, ni1, td[0], ti[0]);
    float od0 = td[0]; int oi0 = ti[0];
    td[0] = e ? nd1 : od0;  ti[0] = e ? ni1 : oi0;
    td[1] = e ? od0 : nd1;  ti[1] = e ? oi0 : ni1;
    td[2] = nd2;            ti[2] = ni2;
}

// merge two sorted top-3 lists (b into a), branchless
__device__ __forceinline__ void merge3(float ad[3], int ai[3],
                                       const float bd[3], const int bi[3]) {
    bool b0 = plt(ad[0], ai[0], bd[0], bi[0]);
    float c0d = b0 ? ad[0] : bd[0];  int c0i = b0 ? ai[0] : bi[0];
    float w0d = b0 ? bd[0] : ad[0];  int w0i = b0 ? bi[0] : ai[0];
    bool b1 = plt(ad[1], ai[1], bd[1], bi[1]);
    float m1d = b1 ? ad[1] : bd[1];  int m1i = b1 ? ai[1] : bi[1];
    float M1d = b1 ? bd[1] : ad[1];  int M1i = b1 ? bi[1] : ai[1];
    bool br1 = plt(w0d, w0i, m1d, m1i);
    float r1d = br1 ? w0d : m1d;     int r1i = br1 ? w0i : m1i;
    float t1d = br1 ? m1d : w0d;     int t1i = br1 ? m1i : w0i; // max(w0,m1)
    bool b2 = plt(ad[2], ai[2], bd[2], bi[2]);
    float t2d = b2 ? ad[2] : bd[2];  int t2i = b2 ? ai[2] : bi[2]; // min(a2,b2)
    bool c1 = plt(M1d, M1i, t1d, t1i);
    float ud = c1 ? M1d : t1d;       int ui = c1 ? M1i : t1i;
    bool c2 = plt(ud, ui, t2d, t2i);
    float r2d = c2 ? ud : t2d;       int r2i = c2 ? ui : t2i;
    ad[0] = c0d; ai[0] = c0i;
    ad[1] = r1d; ai[1] = r1i;
    ad[2] = r2d; ai[2] = r2i;
}

// x-row norms only (wave per row) -> ln.  (R13-proven structure)
__global__ __launch_bounds__(256)
void xnorm_all(const float* __restrict__ x, float* __restrict__ ln,
               int F, int B) {
    int wid  = (blockIdx.x * 256 + threadIdx.x) >> 6;
    int lane = threadIdx.x & 63;
    if (wid >= B) return;
    float s = 0.f;
    #pragma unroll
    for (int k = 0; k < 4; ++k) {
        float v = x[(size_t)wid * F + lane + 64 * k];
        s = fmaf(v, v, s);
    }
    s += __shfl_xor(s, 1);
    s += __shfl_xor(s, 2);
    s += __shfl_xor(s, 4);
    s += __shfl_xor(s, 8);
    s += __shfl_xor(s, 16);
    s += __shfl_xor(s, 32);
    if (lane == 0) ln[wid] = s;
}

// 4x4 micro-tiled distance + top-3; K-chunked staging (2 x 128 f) so LDS
// fits 2 blocks/CU (2 waves/SIMD -> VALU/LDS overlap).  Col norms computed
// cooperatively from staged ts_ (feat-weighted).  Inner loop = R15-proven.
__global__ __launch_bounds__(256)
void knn_split4(const float* __restrict__ x, const float* __restrict__ t,
                const float* __restrict__ feat, const float* __restrict__ ln,
                float* __restrict__ outbuf, int F, int N, int B) {
    __shared__ float xs[RPB * PAD];    // 33.3 KB
    __shared__ float ts_[CCH * PAD];   // 33.3 KB
    __shared__ float fs[256];
    __shared__ float rsum[CCH];

    const int tid = threadIdx.x;
    const int colt = tid & 15;
    const int rowg = tid >> 4;
    const int rowblk = blockIdx.x & 31;          // B/RPB == 32
    const int split  = blockIdx.x >> 5;          // 0..15
    const int row0 = rowblk * RPB;
    const int nslice = N / NSPL;                 // 4096
    const int nbase = split * nslice;

    fs[tid] = feat[tid];               // F == 256 (visible after first barrier)

    const float lvA = ln[row0 + rowg];
    const float lvB = ln[row0 + rowg + 16];
    const float lvC = ln[row0 + rowg + 32];
    const float lvD = ln[row0 + rowg + 48];

    float tdA[3], tdB[3], tdC[3], tdD[3];
    int   tiA[3], tiB[3], tiC[3], tiD[3];
    tdA[0]=tdA[1]=tdA[2]=INFINITY; tiA[0]=tiA[1]=tiA[2]=INT_MAX;
    tdB[0]=tdB[1]=tdB[2]=INFINITY; tiB[0]=tiB[1]=tiB[2]=INT_MAX;
    tdC[0]=tdC[1]=tdC[2]=INFINITY; tiC[0]=tiC[1]=tiC[2]=INT_MAX;
    tdD[0]=tdD[1]=tdD[2]=INFINITY; tiD[0]=tiD[1]=tiD[2]=INT_MAX;

    #pragma unroll 1
    for (int cb = 0; cb < nslice; cb += CCH) {   // 64 col-chunks
        const int n0 = nbase + cb;
        float a00=0.f,a01=0.f,a02=0.f,a03=0.f;
        float a10=0.f,a11=0.f,a12=0.f,a13=0.f;
        float a20=0.f,a21=0.f,a22=0.f,a23=0.f;
        float a30=0.f,a31=0.f,a32=0.f,a33=0.f;

        #pragma unroll 1
        for (int kc = 0; kc < 2; ++kc) {
            const int f0 = kc * KF;
            // stage 64 rows x 128 f of x and t (coalesced: f = tid&127)
            {
                const int fr = tid & 127;
                const int r2 = tid >> 7;         // 0..1
                #pragma unroll 4
                for (int q = 0; q < 32; ++q) {
                    int row = q * 2 + r2;
                    xs[row * PAD + fr] = x[(size_t)(row0 + row) * F + f0 + fr];
                    ts_[row * PAD + fr] = t[(size_t)(n0 + row) * F + f0 + fr];
                }
            }
            __syncthreads();

            // cooperative feat-weighted col norms: 4 threads per col
            {
                const int c = tid >> 2;          // 0..63
                const int g = tid & 3;
                float s = 0.f;
                #pragma unroll 8
                for (int k = 0; k < 32; ++k) {
                    int f = g + 4 * k;
                    float v = ts_[c * PAD + f] * fs[f0 + f];
                    s = fmaf(v, v, s);
                }
                s += __shfl_xor(s, 1);
                s += __shfl_xor(s, 2);
                if (g == 0) { if (kc == 0) rsum[c] = s; else rsum[c] += s; }
            }

            // 4x4 dot over this K-chunk (R15-proven inner loop)
            #pragma unroll 4
            for (int f = 0; f < KF; f += 2) {
                float2 t0 = *(const float2*)&ts_[colt * PAD + f];
                float2 t1 = *(const float2*)&ts_[(colt + 16) * PAD + f];
                float2 t2 = *(const float2*)&ts_[(colt + 32) * PAD + f];
                float2 t3 = *(const float2*)&ts_[(colt + 48) * PAD + f];
                float2 x0 = *(const float2*)&xs[rowg * PAD + f];
                float2 x1 = *(const float2*)&xs[(rowg + 16) * PAD + f];
                float2 x2 = *(const float2*)&xs[(rowg + 32) * PAD + f];
                float2 x3 = *(const float2*)&xs[(rowg + 48) * PAD + f];
                a00 = fmaf(x0.x, t0.x, a00); a00 = fmaf(x0.y, t0.y, a00);
                a01 = fmaf(x0.x, t1.x, a01); a01 = fmaf(x0.y, t1.y, a01);
                a02 = fmaf(x0.x, t2.x, a02); a02 = fmaf(x0.y, t2.y, a02);
                a03 = fmaf(x0.x, t3.x, a03); a03 = fmaf(x0.y, t3.y, a03);
                a10 = fmaf(x1.x, t0.x, a10); a10 = fmaf(x1.y, t0.y, a10);
                a11 = fmaf(x1.x, t1.x, a11); a11 = fmaf(x1.y, t1.y, a11);
                a12 = fmaf(x1.x, t2.x, a12); a12 = fmaf(x1.y, t2.y, a12);
                a13 = fmaf(x1.x, t3.x, a13); a13 = fmaf(x1.y, t3.y, a13);
                a20 = fmaf(x2.x, t0.x, a20); a20 = fmaf(x2.y, t0.y, a20);
                a21 = fmaf(x2.x, t1.x, a21); a21 = fmaf(x2.y, t1.y, a21);
                a22 = fmaf(x2.x, t2.x, a22); a22 = fmaf(x2.y, t2.y, a22);
                a23 = fmaf(x2.x, t3.x, a23); a23 = fmaf(x2.y, t3.y, a23);
                a30 = fmaf(x3.x, t0.x, a30); a30 = fmaf(x3.y, t0.y, a30);
                a31 = fmaf(x3.x, t1.x, a31); a31 = fmaf(x3.y, t1.y, a31);
                a32 = fmaf(x3.x, t2.x, a32); a32 = fmaf(x3.y, t2.y, a32);
                a33 = fmaf(x3.x, t3.x, a33); a33 = fmaf(x3.y, t3.y, a33);
            }
            __syncthreads();   // before next K-chunk restages xs/ts_
        }

        // rsum complete (both kc halves); distances + running top-3
        const float rv0 = rsum[colt];
        const float rv1 = rsum[colt + 16];
        const float rv2 = rsum[colt + 32];
        const float rv3 = rsum[colt + 48];
        const int nc0 = n0 + colt, nc1 = n0 + colt + 16,
                  nc2 = n0 + colt + 32, nc3 = n0 + colt + 48;
        insert3(sqrtf(lvA + rv0) - 2.0f * a00, nc0, tdA, tiA);
        insert3(sqrtf(lvA + rv1) - 2.0f * a01, nc1, tdA, tiA);
        insert3(sqrtf(lvA + rv2) - 2.0f * a02, nc2, tdA, tiA);
        insert3(sqrtf(lvA + rv3) - 2.0f * a03, nc3, tdA, tiA);
        insert3(sqrtf(lvB + rv0) - 2.0f * a10, nc0, tdB, tiB);
        insert3(sqrtf(lvB + rv1) - 2.0f * a11, nc1, tdB, tiB);
        insert3(sqrtf(lvB + rv2) - 2.0f * a12, nc2, tdB, tiB);
        insert3(sqrtf(lvB + rv3) - 2.0f * a13, nc3, tdB, tiB);
        insert3(sqrtf(lvC + rv0) - 2.0f * a20, nc0, tdC, tiC);
        insert3(sqrtf(lvC + rv1) - 2.0f * a21, nc1, tdC, tiC);
        insert3(sqrtf(lvC + rv2) - 2.0f * a22, nc2, tdC, tiC);
        insert3(sqrtf(lvC + rv3) - 2.0f * a23, nc3, tdC, tiC);
        insert3(sqrtf(lvD + rv0) - 2.0f * a30, nc0, tdD, tiD);
        insert3(sqrtf(lvD + rv1) - 2.0f * a31, nc1, tdD, tiD);
        insert3(sqrtf(lvD + rv2) - 2.0f * a32, nc2, tdD, tiD);
        insert3(sqrtf(lvD + rv3) - 2.0f * a33, nc3, tdD, tiD);
        __syncthreads();   // rsum/ts_ reused next chunk
    }

    // merge across the 16 colt threads sharing a row-group (16-aligned lanes)
    #pragma unroll 1
    for (int m = 1; m < 16; m <<= 1) {
        float od[3]; int oi[3];
        #pragma unroll
        for (int s = 0; s < 3; ++s) { od[s] = __shfl_xor(tdA[s], m); oi[s] = __shfl_xor(tiA[s], m); }
        merge3(tdA, tiA, od, oi);
        #pragma unroll
        for (int s = 0; s < 3; ++s) { od[s] = __shfl_xor(tdB[s], m); oi[s] = __shfl_xor(tiB[s], m); }
        merge3(tdB, tiB, od, oi);
        #pragma unroll
        for (int s = 0; s < 3; ++s) { od[s] = __shfl_xor(tdC[s], m); oi[s] = __shfl_xor(tiC[s], m); }
        merge3(tdC, tiC, od, oi);
        #pragma unroll
        for (int s = 0; s < 3; ++s) { od[s] = __shfl_xor(tdD[s], m); oi[s] = __shfl_xor(tiD[s], m); }
        merge3(tdD, tiD, od, oi);
    }
    if (colt == 0) {
        int baseA = ((row0 + rowg)      * NSPL + split) * 6;
        int baseB = ((row0 + rowg + 16) * NSPL + split) * 6;
        int baseC = ((row0 + rowg + 32) * NSPL + split) * 6;
        int baseD = ((row0 + rowg + 48) * NSPL + split) * 6;
        #pragma unroll
        for (int s = 0; s < 3; ++s) {
            outbuf[baseA + s] = tdA[s];  outbuf[baseA + 3 + s] = (float)tiA[s];
            outbuf[baseB + s] = tdB[s];  outbuf[baseB + 3 + s] = (float)tiB[s];
            outbuf[baseC + s] = tdC[s];  outbuf[baseC + 3 + s] = (float)tiC[s];
            outbuf[baseD + s] = tdD[s];  outbuf[baseD + 3 + s] = (float)tiD[s];
        }
    }
}

// Merge NSPL=16 candidate triples per row -> top-3 -> labels -> stash.
// 256 thr = 16 rows x 16 lanes.
__global__ __launch_bounds__(256)
void knn_merge(float* __restrict__ buf, const int* __restrict__ labels,
               int B, int N, int stashBase) {
    const int tid = threadIdx.x;
    const int row = blockIdx.x * 16 + (tid >> 4);
    const int j = tid & 15;
    const int base = (row * NSPL + j) * 6;
    float d[3]; int ii[3];
    #pragma unroll
    for (int s = 0; s < 3; ++s) {
        d[s] = buf[base + s];
        ii[s] = (int)buf[base + 3 + s];
    }
    #pragma unroll
    for (int m = 1; m < 16; m <<= 1) {
        float od[3]; int oi[3];
        #pragma unroll
        for (int s = 0; s < 3; ++s) { od[s] = __shfl_xor(d[s], m); oi[s] = __shfl_xor(ii[s], m); }
        merge3(d, ii, od, oi);
    }
    if (j == 0) {
        #pragma unroll
        for (int s = 0; s < 3; ++s) {
            int idx = ii[s];
            idx = idx < 0 ? 0 : (idx >= N ? N - 1 : idx);   // never fault
            buf[stashBase + row * 3 + s] = (float)labels[idx];
        }
    }
}

// one-hot rows [0, rowsMain): reads stash, never writes it.  (proven)
__global__ void out_main(float* __restrict__ out, int B, int L,
                         int stashBase, int rowsMain) {
    int tid = blockIdx.x * blockDim.x + threadIdx.x;
    if (tid >= rowsMain * L) return;
    int i = tid / L, c = tid - i * L;
    int s = (int)out[stashBase + i] + (int)out[stashBase + B + i]
          + (int)out[stashBase + 2 * B + i];
    out[tid] = (c == s / 3) ? 1.0f : 0.0f;
}

// single block: buffers needed stash into LDS, barriers, overwrites tail. (proven)
__global__ __launch_bounds__(256)
void out_tail(float* __restrict__ out, int B, int L,
              int stashBase, int rowsMain) {
    __shared__ int l0[128], l1[128], l2[128];
    int nt = B - rowsMain;
    for (int q = threadIdx.x; q < nt * 3; q += 256) {
        int j = q / nt, i = q - j * nt;
        int v = (int)out[stashBase + j * B + rowsMain + i];
        if (j == 0) l0[i] = v; else if (j == 1) l1[i] = v; else l2[i] = v;
    }
    __syncthreads();
    int base = rowsMain * L;
    for (int e = threadIdx.x; e < B * L - base; e += 256) {
        int rr = (base + e) / L - rowsMain, c = (base + e) % L;
        int s = l0[rr] + l1[rr] + l2[rr];
        out[base + e] = (c == s / 3) ? 1.0f : 0.0f;
    }
}

extern "C" void kernel_launch(void* const* d_in, const int* in_sizes, int n_in,
                              void* d_out, int out_size, void* d_ws, size_t ws_size,
                              hipStream_t stream) {
    const float* x      = (const float*)d_in[0];
    const float* t      = (const float*)d_in[1];
    const float* feat   = (const float*)d_in[2];
    const int*   labels = (const int*)d_in[3];
    float*       out    = (float*)d_out;
    const int F = in_sizes[2];           // 256
    const int B = in_sizes[0] / F;       // 2048
    const int N = in_sizes[3];           // 65536
    const int L = out_size / B;          // 100

    const int stashBase = out_size - 3 * B;   // 198656
    const int rowsMain  = stashBase / L;      // 1986
    // scratch layout in d_out (floats):
    //   cand  [0, 196608) = B*NSPL*6 ; ln [196608, 198656) ; stash [198656, 204800)
    float* cand = out;
    float* ln   = out + (size_t)B * NSPL * 6;  // 196608

    xnorm_all<<<(B * 64 + 255) / 256, 256, 0, stream>>>(x, ln, F, B);

    const int nblk = (B / RPB) * NSPL;        // 512 (2 blocks/CU)
    knn_split4<<<nblk, 256, 0, stream>>>(x, t, feat, ln, cand, F, N, B);
    knn_merge<<<B / 16, 256, 0, stream>>>(out, labels, B, N, stashBase);
    out_main<<<(rowsMain * L + 255) / 256, 256, 0, stream>>>(
        out, B, L, stashBase, rowsMain);
    out_tail<<<1, 256, 0, stream>>>(out, B, L, stashBase, rowsMain);
}

// Round 17
// 1585.986 us; speedup vs baseline: 20.9799x; 1.0435x over previous
//
#include <hip/hip_runtime.h>
#include <math.h>
#include <limits.h>

#define RPB 64     // x-rows per block
#define CCH 64     // train cols per chunk
#define KF  128    // f per K-chunk (2 chunks cover F=256)
#define NSPL 16    // N-splits (grid = 32 rowblk x 16 = 512 blocks)
#define PAD 130    // LDS row stride in floats (even -> 8B-aligned float2)

typedef float f32x2 __attribute__((ext_vector_type(2)));

// lexicographic (distance, index) compare == jax.lax.top_k stable tie-break
__device__ __forceinline__ bool plt(float da, int ia, float db, int ib) {
    return (da < db) || ((da == db) && (ia < ib));
}

// branchless insert of candidate (d,n) into sorted ascending top-3
__device__ __forceinline__ void insert3(float d, int n, float td[3], int ti[3]) {
    bool b = plt(d, n, td[2], ti[2]);
    float d2 = b ? d : td[2];  int i2 = b ? n : ti[2];
    bool c = plt(d2, i2, td[1], ti[1]);
    float nd1 = c ? d2 : td[1];    int ni1 = c ? i2 : ti[1];
    float nd2 = c ? td[1] : d2;    int ni2 = c ? ti[1] : i2;
    bool e = plt(nd1, ni1, td[0], ti[0]);
    float od0 = td[0]; int oi0 = ti[0];
    td[0] = e ? nd1 : od0;  ti[0] = e ? ni1 : oi0;
    td[1] = e ? od0 : nd1;  ti[1] = e ? oi0 : ni1;
    td[2] = nd2;            ti[2] = ni2;
}

// merge two sorted top-3 lists (b into a), branchless
__device__ __forceinline__ void merge3(float ad[3], int ai[3],
                                       const float bd[3], const int bi[3]) {
    bool b0 = plt(ad[0], ai[0], bd[0], bi[0]);
    float c0d = b0 ? ad[0] : bd[0];  int c0i = b0 ? ai[0] : bi[0];
    float w0d = b0 ? bd[0] : ad[0];  int w0i = b0 ? bi[0] : ai[0];
    bool b1 = plt(ad[1], ai[1], bd[1], bi[1]);
    float m1d = b1 ? ad[1] : bd[1];  int m1i = b1 ? ai[1] : bi[1];
    float M1d = b1 ? bd[1] : ad[1];  int M1i = b1 ? bi[1] : ai[1];
    bool br1 = plt(w0d, w0i, m1d, m1i);
    float r1d = br1 ? w0d : m1d;     int r1i = br1 ? w0i : m1i;
    float t1d = br1 ? m1d : w0d;     int t1i = br1 ? m1i : w0i; // max(w0,m1)
    bool b2 = plt(ad[2], ai[2], bd[2], bi[2]);
    float t2d = b2 ? ad[2] : bd[2];  int t2i = b2 ? ai[2] : bi[2]; // min(a2,b2)
    bool c1 = plt(M1d, M1i, t1d, t1i);
    float ud = c1 ? M1d : t1d;       int ui = c1 ? M1i : t1i;
    bool c2 = plt(ud, ui, t2d, t2i);
    float r2d = c2 ? ud : t2d;       int r2i = c2 ? ui : t2i;
    ad[0] = c0d; ai[0] = c0i;
    ad[1] = r1d; ai[1] = r1i;
    ad[2] = r2d; ai[2] = r2i;
}

// x-row norms only (wave per row) -> ln.  (R13-proven structure)
__global__ __launch_bounds__(256)
void xnorm_all(const float* __restrict__ x, float* __restrict__ ln,
               int F, int B) {
    int wid  = (blockIdx.x * 256 + threadIdx.x) >> 6;
    int lane = threadIdx.x & 63;
    if (wid >= B) return;
    float s = 0.f;
    #pragma unroll
    for (int k = 0; k < 4; ++k) {
        float v = x[(size_t)wid * F + lane + 64 * k];
        s = fmaf(v, v, s);
    }
    s += __shfl_xor(s, 1);
    s += __shfl_xor(s, 2);
    s += __shfl_xor(s, 4);
    s += __shfl_xor(s, 8);
    s += __shfl_xor(s, 16);
    s += __shfl_xor(s, 32);
    if (lane == 0) ln[wid] = s;
}

// 4x4 micro-tiled distance + top-3; K-chunked staging (R16-proven geometry);
// inner loop upgraded to packed f32x2 FMA (v_pk_fma_f32: 2 FMAs/instr).
__global__ __launch_bounds__(256)
void knn_split4(const float* __restrict__ x, const float* __restrict__ t,
                const float* __restrict__ feat, const float* __restrict__ ln,
                float* __restrict__ outbuf, int F, int N, int B) {
    __shared__ float xs[RPB * PAD];    // 33.3 KB
    __shared__ float ts_[CCH * PAD];   // 33.3 KB
    __shared__ float fs[256];
    __shared__ float rsum[CCH];

    const int tid = threadIdx.x;
    const int colt = tid & 15;
    const int rowg = tid >> 4;
    const int rowblk = blockIdx.x & 31;          // B/RPB == 32
    const int split  = blockIdx.x >> 5;          // 0..15
    const int row0 = rowblk * RPB;
    const int nslice = N / NSPL;                 // 4096
    const int nbase = split * nslice;

    fs[tid] = feat[tid];               // F == 256 (visible after first barrier)

    const float lvA = ln[row0 + rowg];
    const float lvB = ln[row0 + rowg + 16];
    const float lvC = ln[row0 + rowg + 32];
    const float lvD = ln[row0 + rowg + 48];

    float tdA[3], tdB[3], tdC[3], tdD[3];
    int   tiA[3], tiB[3], tiC[3], tiD[3];
    tdA[0]=tdA[1]=tdA[2]=INFINITY; tiA[0]=tiA[1]=tiA[2]=INT_MAX;
    tdB[0]=tdB[1]=tdB[2]=INFINITY; tiB[0]=tiB[1]=tiB[2]=INT_MAX;
    tdC[0]=tdC[1]=tdC[2]=INFINITY; tiC[0]=tiC[1]=tiC[2]=INT_MAX;
    tdD[0]=tdD[1]=tdD[2]=INFINITY; tiD[0]=tiD[1]=tiD[2]=INT_MAX;

    #pragma unroll 1
    for (int cb = 0; cb < nslice; cb += CCH) {   // 64 col-chunks
        const int n0 = nbase + cb;
        // packed pairwise accumulators (even-f / odd-f partial sums)
        f32x2 v00 = {0.f, 0.f}, v01 = {0.f, 0.f}, v02 = {0.f, 0.f}, v03 = {0.f, 0.f};
        f32x2 v10 = {0.f, 0.f}, v11 = {0.f, 0.f}, v12 = {0.f, 0.f}, v13 = {0.f, 0.f};
        f32x2 v20 = {0.f, 0.f}, v21 = {0.f, 0.f}, v22 = {0.f, 0.f}, v23 = {0.f, 0.f};
        f32x2 v30 = {0.f, 0.f}, v31 = {0.f, 0.f}, v32 = {0.f, 0.f}, v33 = {0.f, 0.f};

        #pragma unroll 1
        for (int kc = 0; kc < 2; ++kc) {
            const int f0 = kc * KF;
            // stage 64 rows x 128 f of x and t (coalesced: f = tid&127)
            {
                const int fr = tid & 127;
                const int r2 = tid >> 7;         // 0..1
                #pragma unroll 4
                for (int q = 0; q < 32; ++q) {
                    int row = q * 2 + r2;
                    xs[row * PAD + fr] = x[(size_t)(row0 + row) * F + f0 + fr];
                    ts_[row * PAD + fr] = t[(size_t)(n0 + row) * F + f0 + fr];
                }
            }
            __syncthreads();

            // cooperative feat-weighted col norms: 4 threads per col
            {
                const int c = tid >> 2;          // 0..63
                const int g = tid & 3;
                float s = 0.f;
                #pragma unroll 8
                for (int k = 0; k < 32; ++k) {
                    int f = g + 4 * k;
                    float v = ts_[c * PAD + f] * fs[f0 + f];
                    s = fmaf(v, v, s);
                }
                s += __shfl_xor(s, 1);
                s += __shfl_xor(s, 2);
                if (g == 0) { if (kc == 0) rsum[c] = s; else rsum[c] += s; }
            }

            // 4x4 dot over this K-chunk: 8 ds_read_b64 -> 16 v_pk_fma_f32
            #pragma unroll 4
            for (int f = 0; f < KF; f += 2) {
                f32x2 t0 = *(const f32x2*)&ts_[colt * PAD + f];
                f32x2 t1 = *(const f32x2*)&ts_[(colt + 16) * PAD + f];
                f32x2 t2 = *(const f32x2*)&ts_[(colt + 32) * PAD + f];
                f32x2 t3 = *(const f32x2*)&ts_[(colt + 48) * PAD + f];
                f32x2 x0 = *(const f32x2*)&xs[rowg * PAD + f];
                f32x2 x1 = *(const f32x2*)&xs[(rowg + 16) * PAD + f];
                f32x2 x2 = *(const f32x2*)&xs[(rowg + 32) * PAD + f];
                f32x2 x3 = *(const f32x2*)&xs[(rowg + 48) * PAD + f];
                v00 = __builtin_elementwise_fma(x0, t0, v00);
                v01 = __builtin_elementwise_fma(x0, t1, v01);
                v02 = __builtin_elementwise_fma(x0, t2, v02);
                v03 = __builtin_elementwise_fma(x0, t3, v03);
                v10 = __builtin_elementwise_fma(x1, t0, v10);
                v11 = __builtin_elementwise_fma(x1, t1, v11);
                v12 = __builtin_elementwise_fma(x1, t2, v12);
                v13 = __builtin_elementwise_fma(x1, t3, v13);
                v20 = __builtin_elementwise_fma(x2, t0, v20);
                v21 = __builtin_elementwise_fma(x2, t1, v21);
                v22 = __builtin_elementwise_fma(x2, t2, v22);
                v23 = __builtin_elementwise_fma(x2, t3, v23);
                v30 = __builtin_elementwise_fma(x3, t0, v30);
                v31 = __builtin_elementwise_fma(x3, t1, v31);
                v32 = __builtin_elementwise_fma(x3, t2, v32);
                v33 = __builtin_elementwise_fma(x3, t3, v33);
            }
            __syncthreads();   // before next K-chunk restages xs/ts_
        }

        // fold packed partials, then distances + running top-3
        const float a00 = v00[0] + v00[1], a01 = v01[0] + v01[1];
        const float a02 = v02[0] + v02[1], a03 = v03[0] + v03[1];
        const float a10 = v10[0] + v10[1], a11 = v11[0] + v11[1];
        const float a12 = v12[0] + v12[1], a13 = v13[0] + v13[1];
        const float a20 = v20[0] + v20[1], a21 = v21[0] + v21[1];
        const float a22 = v22[0] + v22[1], a23 = v23[0] + v23[1];
        const float a30 = v30[0] + v30[1], a31 = v31[0] + v31[1];
        const float a32 = v32[0] + v32[1], a33 = v33[0] + v33[1];

        const float rv0 = rsum[colt];
        const float rv1 = rsum[colt + 16];
        const float rv2 = rsum[colt + 32];
        const float rv3 = rsum[colt + 48];
        const int nc0 = n0 + colt, nc1 = n0 + colt + 16,
                  nc2 = n0 + colt + 32, nc3 = n0 + colt + 48;
        insert3(sqrtf(lvA + rv0) - 2.0f * a00, nc0, tdA, tiA);
        insert3(sqrtf(lvA + rv1) - 2.0f * a01, nc1, tdA, tiA);
        insert3(sqrtf(lvA + rv2) - 2.0f * a02, nc2, tdA, tiA);
        insert3(sqrtf(lvA + rv3) - 2.0f * a03, nc3, tdA, tiA);
        insert3(sqrtf(lvB + rv0) - 2.0f * a10, nc0, tdB, tiB);
        insert3(sqrtf(lvB + rv1) - 2.0f * a11, nc1, tdB, tiB);
        insert3(sqrtf(lvB + rv2) - 2.0f * a12, nc2, tdB, tiB);
        insert3(sqrtf(lvB + rv3) - 2.0f * a13, nc3, tdB, tiB);
        insert3(sqrtf(lvC + rv0) - 2.0f * a20, nc0, tdC, tiC);
        insert3(sqrtf(lvC + rv1) - 2.0f * a21, nc1, tdC, tiC);
        insert3(sqrtf(lvC + rv2) - 2.0f * a22, nc2, tdC, tiC);
        insert3(sqrtf(lvC + rv3) - 2.0f * a23, nc3, tdC, tiC);
        insert3(sqrtf(lvD + rv0) - 2.0f * a30, nc0, tdD, tiD);
        insert3(sqrtf(lvD + rv1) - 2.0f * a31, nc1, tdD, tiD);
        insert3(sqrtf(lvD + rv2) - 2.0f * a32, nc2, tdD, tiD);
        insert3(sqrtf(lvD + rv3) - 2.0f * a33, nc3, tdD, tiD);
        __syncthreads();   // rsum/ts_ reused next chunk
    }

    // merge across the 16 colt threads sharing a row-group (16-aligned lanes)
    #pragma unroll 1
    for (int m = 1; m < 16; m <<= 1) {
        float od[3]; int oi[3];
        #pragma unroll
        for (int s = 0; s < 3; ++s) { od[s] = __shfl_xor(tdA[s], m); oi[s] = __shfl_xor(tiA[s], m); }
        merge3(tdA, tiA, od, oi);
        #pragma unroll
        for (int s = 0; s < 3; ++s) { od[s] = __shfl_xor(tdB[s], m); oi[s] = __shfl_xor(tiB[s], m); }
        merge3(tdB, tiB, od, oi);
        #pragma unroll
        for (int s = 0; s < 3; ++s) { od[s] = __shfl_xor(tdC[s], m); oi[s] = __shfl_xor(tiC[s], m); }
        merge3(tdC, tiC, od, oi);
        #pragma unroll
        for (int s = 0; s < 3; ++s) { od[s] = __shfl_xor(tdD[s], m); oi[s] = __shfl_xor(tiD[s], m); }
        merge3(tdD, tiD, od, oi);
    }
    if (colt == 0) {
        int baseA = ((row0 + rowg)      * NSPL + split) * 6;
        int baseB = ((row0 + rowg + 16) * NSPL + split) * 6;
        int baseC = ((row0 + rowg + 32) * NSPL + split) * 6;
        int baseD = ((row0 + rowg + 48) * NSPL + split) * 6;
        #pragma unroll
        for (int s = 0; s < 3; ++s) {
            outbuf[baseA + s] = tdA[s];  outbuf[baseA + 3 + s] = (float)tiA[s];
            outbuf[baseB + s] = tdB[s];  outbuf[baseB + 3 + s] = (float)tiB[s];
            outbuf[baseC + s] = tdC[s];  outbuf[baseC + 3 + s] = (float)tiC[s];
            outbuf[baseD + s] = tdD[s];  outbuf[baseD + 3 + s] = (float)tiD[s];
        }
    }
}

// Merge NSPL=16 candidate triples per row -> top-3 -> labels -> stash.
// 256 thr = 16 rows x 16 lanes.
__global__ __launch_bounds__(256)
void knn_merge(float* __restrict__ buf, const int* __restrict__ labels,
               int B, int N, int stashBase) {
    const int tid = threadIdx.x;
    const int row = blockIdx.x * 16 + (tid >> 4);
    const int j = tid & 15;
    const int base = (row * NSPL + j) * 6;
    float d[3]; int ii[3];
    #pragma unroll
    for (int s = 0; s < 3; ++s) {
        d[s] = buf[base + s];
        ii[s] = (int)buf[base + 3 + s];
    }
    #pragma unroll
    for (int m = 1; m < 16; m <<= 1) {
        float od[3]; int oi[3];
        #pragma unroll
        for (int s = 0; s < 3; ++s) { od[s] = __shfl_xor(d[s], m); oi[s] = __shfl_xor(ii[s], m); }
        merge3(d, ii, od, oi);
    }
    if (j == 0) {
        #pragma unroll
        for (int s = 0; s < 3; ++s) {
            int idx = ii[s];
            idx = idx < 0 ? 0 : (idx >= N ? N - 1 : idx);   // never fault
            buf[stashBase + row * 3 + s] = (float)labels[idx];
        }
    }
}

// one-hot rows [0, rowsMain): reads stash, never writes it.  (proven)
__global__ void out_main(float* __restrict__ out, int B, int L,
                         int stashBase, int rowsMain) {
    int tid = blockIdx.x * blockDim.x + threadIdx.x;
    if (tid >= rowsMain * L) return;
    int i = tid / L, c = tid - i * L;
    int s = (int)out[stashBase + i] + (int)out[stashBase + B + i]
          + (int)out[stashBase + 2 * B + i];
    out[tid] = (c == s / 3) ? 1.0f : 0.0f;
}

// single block: buffers needed stash into LDS, barriers, overwrites tail. (proven)
__global__ __launch_bounds__(256)
void out_tail(float* __restrict__ out, int B, int L,
              int stashBase, int rowsMain) {
    __shared__ int l0[128], l1[128], l2[128];
    int nt = B - rowsMain;
    for (int q = threadIdx.x; q < nt * 3; q += 256) {
        int j = q / nt, i = q - j * nt;
        int v = (int)out[stashBase + j * B + rowsMain + i];
        if (j == 0) l0[i] = v; else if (j == 1) l1[i] = v; else l2[i] = v;
    }
    __syncthreads();
    int base = rowsMain * L;
    for (int e = threadIdx.x; e < B * L - base; e += 256) {
        int rr = (base + e) / L - rowsMain, c = (base + e) % L;
        int s = l0[rr] + l1[rr] + l2[rr];
        out[base + e] = (c == s / 3) ? 1.0f : 0.0f;
    }
}

extern "C" void kernel_launch(void* const* d_in, const int* in_sizes, int n_in,
                              void* d_out, int out_size, void* d_ws, size_t ws_size,
                              hipStream_t stream) {
    const float* x      = (const float*)d_in[0];
    const float* t      = (const float*)d_in[1];
    const float* feat   = (const float*)d_in[2];
    const int*   labels = (const int*)d_in[3];
    float*       out    = (float*)d_out;
    const int F = in_sizes[2];           // 256
    const int B = in_sizes[0] / F;       // 2048
    const int N = in_sizes[3];           // 65536
    const int L = out_size / B;          // 100

    const int stashBase = out_size - 3 * B;   // 198656
    const int rowsMain  = stashBase / L;      // 1986
    // scratch layout in d_out (floats):
    //   cand  [0, 196608) = B*NSPL*6 ; ln [196608, 198656) ; stash [198656, 204800)
    float* cand = out;
    float* ln   = out + (size_t)B * NSPL * 6;  // 196608

    xnorm_all<<<(B * 64 + 255) / 256, 256, 0, stream>>>(x, ln, F, B);

    const int nblk = (B / RPB) * NSPL;        // 512 (2 blocks/CU)
    knn_split4<<<nblk, 256, 0, stream>>>(x, t, feat, ln, cand, F, N, B);
    knn_merge<<<B / 16, 256, 0, stream>>>(out, labels, B, N, stashBase);
    out_main<<<(rowsMain * L + 255) / 256, 256, 0, stream>>>(
        out, B, L, stashBase, rowsMain);
    out_tail<<<1, 256, 0, stream>>>(out, B, L, stashBase, rowsMain);
}